// Round 13
// baseline (1113.746 us; speedup 1.0000x reference)
//
#include <hip/hip_runtime.h>
#include <hip/hip_fp16.h>
#include <math.h>

#define HEADS 8
#define CDIM 128
#define HC 1024
#define EMBD 256
#define NGRAPH 64
#define QSCALE2 0.12751744f             // (1/sqrt(128)) * log2(e): exp2-domain logits

typedef unsigned short u16;
typedef short s8v __attribute__((ext_vector_type(8)));
typedef float f4v __attribute__((ext_vector_type(4)));
typedef _Float16 h2v __attribute__((ext_vector_type(2)));

__device__ __forceinline__ float b2f(u16 u) {
  union { unsigned int i; float f; } v; v.i = ((unsigned int)u) << 16; return v.f;
}
__device__ __forceinline__ u16 f2b(float f) {
  union { float f; unsigned int i; } v; v.f = f;
  unsigned int i = v.i;
  unsigned int r = (i + 0x7FFFu + ((i >> 16) & 1u)) >> 16;
  return (u16)r;
}
__device__ __forceinline__ u16 f2h(float f) {
  __half h = __float2half(f);
  return *(u16*)&h;
}

union U4H { uint4 u; h2v h[4]; };

// ---------------- embedding gather + f32->bf16 ----------------
__global__ __launch_bounds__(256) void embed_kernel(
    const int* __restrict__ x, const float* __restrict__ emb,
    u16* __restrict__ h0, int N)
{
  int idx = blockIdx.x * 256 + threadIdx.x;
  if (idx >= N * (EMBD / 4)) return;
  int n = idx >> 6;
  int j = (idx & 63) * 4;
  int vid = x[n];
  float4 f = *(const float4*)&emb[(size_t)vid * EMBD + j];
  ushort4 u;
  u.x = f2b(f.x); u.y = f2b(f.y); u.z = f2b(f.z); u.w = f2b(f.w);
  *(ushort4*)&h0[(size_t)n * EMBD + j] = u;
}

// ---------------- Ws -> fragment-swizzled bf16 B ----------------
__global__ __launch_bounds__(256) void build_WsT_swz(
    const float* __restrict__ in, u16* __restrict__ out, int K)
{
  const int KS = K / 32;
  int nt = blockIdx.x;
  int ks = blockIdx.y;
  int t = threadIdx.x;
  int lane = t & 63, ni = t >> 6;
  int q4 = lane >> 4, cn = lane & 15;
  int colL = nt * 64 + ni * 16 + cn;
  int kbase = ks * 32 + q4 * 8;
  u16 tmp[8];
#pragma unroll
  for (int e8 = 0; e8 < 8; e8++) tmp[e8] = f2b(in[(size_t)(kbase + e8) * CDIM + colL]);
  size_t base = ((((size_t)nt * KS + ks) * 4 + ni) * 64 + lane) * 8;
  *(uint4*)&out[base] = *(uint4*)tmp;
}

// ---------------- chunked qkv^T weights -> fragment-swizzled bf16 (QSCALE2 in q) ----------------
__global__ __launch_bounds__(256) void build_qkvT_swz(
    const float* __restrict__ Wq, const float* __restrict__ Wk, const float* __restrict__ Wv,
    u16* __restrict__ WT, int K, int hpc)
{
  __shared__ u16 tile[64][130];
  const int KS = K / 32;
  int rg0 = blockIdx.x * 128;
  int kk0 = blockIdx.y * 64;
  int chunkCols = hpc * 384;
  int chunk = rg0 / chunkCols;
  int within = rg0 - chunk * chunkCols;
  int head = chunk * hpc + within / 384;
  int sub = within % 384;
  int sect = sub >> 7;
  const float* W = (sect == 0) ? Wq : (sect == 1 ? Wk : Wv);
  float scale = (sect == 0) ? QSCALE2 : 1.0f;
  int cc0 = head * CDIM;
  int t = threadIdx.x;
  int ci = t & 127, k2 = t >> 7;
#pragma unroll
  for (int ii = 0; ii < 32; ii++) {
    int ki = k2 + ii * 2;
    tile[ki][ci] = f2b(W[(size_t)(kk0 + ki) * HC + cc0 + ci] * scale);
  }
  __syncthreads();

  int lane = t & 63, ni = t >> 6;
  int q4 = lane >> 4, cn = lane & 15;
  int ntBase = rg0 >> 6;
#pragma unroll
  for (int ntd = 0; ntd < 2; ntd++) {
#pragma unroll
    for (int ksd = 0; ksd < 2; ksd++) {
      int colL = ntd * 64 + ni * 16 + cn;
      int kL = ksd * 32 + q4 * 8;
      u16 tmp[8];
#pragma unroll
      for (int e8 = 0; e8 < 8; e8++) tmp[e8] = tile[kL + e8][colL];
      size_t base = ((((size_t)(ntBase + ntd) * KS + (kk0 >> 5) + ksd) * 4 + ni) * 64 + lane) * 8;
      *(uint4*)&WT[base] = *(uint4*)tmp;
    }
  }
}
__global__ __launch_bounds__(256) void build_qkvb(
    const float* __restrict__ bq, const float* __restrict__ bk, const float* __restrict__ bv,
    float* __restrict__ bT, int hpc)
{
  int rg = blockIdx.x * 256 + threadIdx.x;
  if (rg >= 3 * HC) return;
  int chunkCols = hpc * 384;
  int chunk = rg / chunkCols;
  int within = rg - chunk * chunkCols;
  int head = chunk * hpc + within / 384;
  int sub = within % 384;
  int sect = sub >> 7;
  int cc = head * CDIM + (sub & 127);
  bT[rg] = (sect == 0) ? bq[cc] * QSCALE2 : (sect == 1 ? bk[cc] : bv[cc]);
}

// ---------------- CSR build ----------------
__global__ __launch_bounds__(256) void deg_kernel(const int* __restrict__ ei, int* __restrict__ deg, int E) {
  int e = blockIdx.x * 256 + threadIdx.x;
  if (e < E) atomicAdd(&deg[ei[E + e]], 1);
}
__global__ __launch_bounds__(256) void scan1_kernel(const int* __restrict__ deg, int* __restrict__ row_ptr,
                                                    int* __restrict__ bsum, int N) {
  __shared__ int sb[256];
  int t = threadIdx.x, idx = blockIdx.x * 256 + t;
  int x = (idx < N) ? deg[idx] : 0;
  sb[t] = x; __syncthreads();
  for (int off = 1; off < 256; off <<= 1) {
    int y = (t >= off) ? sb[t - off] : 0;
    __syncthreads(); sb[t] += y; __syncthreads();
  }
  if (idx < N) row_ptr[idx + 1] = sb[t];
  if (t == 255) bsum[blockIdx.x] = sb[255];
  if (idx == 0) row_ptr[0] = 0;
}
__global__ __launch_bounds__(256) void scan2_kernel(int* __restrict__ bsum, int B) {
  __shared__ int sb[256];
  int t = threadIdx.x;
  int x = (t < B) ? bsum[t] : 0;
  sb[t] = x; __syncthreads();
  for (int off = 1; off < 256; off <<= 1) {
    int y = (t >= off) ? sb[t - off] : 0;
    __syncthreads(); sb[t] += y; __syncthreads();
  }
  if (t < B) bsum[t] = sb[t] - x;   // exclusive
}
__global__ __launch_bounds__(256) void scan3_kernel(int* __restrict__ row_ptr, const int* __restrict__ bsum, int N) {
  int idx = blockIdx.x * 256 + threadIdx.x;
  if (idx < N) row_ptr[idx + 1] += bsum[idx >> 8];
}
__global__ __launch_bounds__(256) void scatter_kernel(const int* __restrict__ ei,
                                                      const int* __restrict__ row_ptr,
                                                      int* __restrict__ fill, int* __restrict__ col, int E) {
  int e = blockIdx.x * 256 + threadIdx.x;
  if (e >= E) return;
  int d = ei[E + e];
  int pos = row_ptr[d] + atomicAdd(&fill[d], 1);
  col[pos] = ei[e];
}
__global__ void gb_kernel(const int* __restrict__ batch, int* __restrict__ gb, int N) {
  int g = threadIdx.x;
  if (g > NGRAPH) return;
  int lo = 0, hi = N;
  while (lo < hi) { int mid = (lo + hi) >> 1; if (batch[mid] < g) lo = mid + 1; else hi = mid; }
  gb[g] = lo;
}

// ---------------- GEMM: A in LDS once; B fragment-swizzled from L2; qkv + xr merged ----------------
template <int K>
__global__ __launch_bounds__(256, 3) void gemm_lds(
    const u16* __restrict__ A, const u16* __restrict__ Bq, const u16* __restrict__ Bx,
    int col0tile, int xrTile0,
    const float* __restrict__ biasQ, const float* __restrict__ biasX,
    u16* __restrict__ outQ, u16* __restrict__ outX,
    int M, int nTiles)
{
  const int LDK = K + 8;
  const int KS = K / 32;
  __shared__ __align__(16) u16 As[64 * LDK];
  int t = threadIdx.x, lane = t & 63, w = t >> 6;
  int q4 = lane >> 4, cn = lane & 15;
  int m0 = blockIdx.y * 64;
  int ntL = blockIdx.x * 4 + w;
  bool wActive = ntL < nTiles;
  int ntG = col0tile + ntL;
  bool isXr = ntG >= xrTile0;

  if (m0 + 64 <= M) {
    const u16* Ablk = A + (size_t)m0 * K;
#pragma unroll
    for (int ii = 0; ii < K / 32; ii++) {
      int g = (ii * 256 + t) * 8;
      int r = g / K, c = g - r * K;
      *(uint4*)&As[r * LDK + c] = *(const uint4*)(Ablk + g);
    }
  } else {
#pragma unroll
    for (int ii = 0; ii < K / 32; ii++) {
      int g = (ii * 256 + t) * 8;
      int r = g / K, c = g - r * K;
      int gr = m0 + r; if (gr >= M) gr = M - 1;
      *(uint4*)&As[r * LDK + c] = *(const uint4*)(A + (size_t)gr * K + c);
    }
  }
  __syncthreads();

  if (!wActive) return;

  f4v acc[4][4] = {};
  const u16* bb = isXr
      ? Bx + ((size_t)(ntG - xrTile0) * KS * 4) * 512 + lane * 8
      : Bq + ((size_t)ntG * KS * 4) * 512 + lane * 8;
#pragma unroll
  for (int ks = 0; ks < KS; ks++) {
    s8v bf[4], af[4];
#pragma unroll
    for (int ni = 0; ni < 4; ni++)
      bf[ni] = *(const s8v*)(bb + ((size_t)ks * 4 + ni) * 512);
#pragma unroll
    for (int mi = 0; mi < 4; mi++)
      af[mi] = *(const s8v*)&As[(mi * 16 + cn) * LDK + ks * 32 + q4 * 8];
#pragma unroll
    for (int mi = 0; mi < 4; mi++)
#pragma unroll
      for (int ni = 0; ni < 4; ni++)
        acc[mi][ni] = __builtin_amdgcn_mfma_f32_16x16x32_bf16(af[mi], bf[ni], acc[mi][ni], 0, 0, 0);
  }

  u16* obase = isXr ? outX + (size_t)(ntG - xrTile0) * M * 64
                    : outQ + (size_t)ntL * M * 64;
  float bv[4];
#pragma unroll
  for (int ni = 0; ni < 4; ni++)
    bv[ni] = isXr ? biasX[(ntG - xrTile0) * 64 + ni * 16 + cn]
                  : biasQ[ntG * 64 + ni * 16 + cn];
#pragma unroll
  for (int mi = 0; mi < 4; mi++) {
#pragma unroll
    for (int j = 0; j < 4; j++) {
      int gm = m0 + mi * 16 + q4 * 4 + j;
      if (gm < M) {
#pragma unroll
        for (int ni = 0; ni < 4; ni++) {
          float val = acc[mi][ni][j] + bv[ni];
          obase[(size_t)gm * 64 + ni * 16 + cn] = isXr ? f2b(val) : f2h(val);
        }
      }
    }
  }
}

// ---------------- attention chunk: f16 qkv, 8 edges/trip, 16 lanes/edge, merged rescale ----------------
template <int HPC>
__global__ __launch_bounds__(256) void attn_chunk_kernel(
    const u16* __restrict__ qkv,
    const int* __restrict__ row_ptr, const int* __restrict__ col,
    float* __restrict__ outacc, int N, int first)
{
  int t = threadIdx.x;
  int w = t >> 6, lane = t & 63;
  int g = lane >> 4, i = lane & 15;     // edge group 0..3, channel sub (8 ch/lane)
  int n, j;
  if (HPC == 4)      { n = blockIdx.x;                 j = w; }
  else if (HPC == 2) { n = blockIdx.x * 2 + (w >> 1);  j = w & 1; }
  else               { n = blockIdx.x * 4 + w;         j = 0; }
  bool active = (HPC == 4) ? true : (n < N);

  int itile = i >> 3, ioff = (i & 7) * 8;
  const u16* qb = qkv + (size_t)(j * 6 + 0 + itile) * N * 64 + ioff;
  const u16* kb = qkv + (size_t)(j * 6 + 2 + itile) * N * 64 + ioff;
  const u16* vb = qkv + (size_t)(j * 6 + 4 + itile) * N * 64 + ioff;

  float acc[8] = {};
  float m = -INFINITY, l = 0.f;
  if (active) {
    U4H qu; qu.u = *(const uint4*)(qb + (size_t)n * 64);
    int e0 = row_ptr[n], e1 = row_ptr[n + 1];
    for (int eb = e0; eb < e1; eb += 8) {
      int egA = eb + g, egB = eb + 4 + g;
      bool vA = egA < e1, vB = egB < e1;
      int sA = col[vA ? egA : e1 - 1];
      int sB = col[vB ? egB : e1 - 1];
      U4H kuA, vuA, kuB, vuB;
      kuA.u = *(const uint4*)(kb + (size_t)sA * 64);
      kuB.u = *(const uint4*)(kb + (size_t)sB * 64);
      vuA.u = *(const uint4*)(vb + (size_t)sA * 64);
      vuB.u = *(const uint4*)(vb + (size_t)sB * 64);

      float pA, pB;
#if defined(__has_builtin) && __has_builtin(__builtin_amdgcn_fdot2)
      pA = __builtin_amdgcn_fdot2(kuA.h[0], qu.h[0], 0.f, false);
      pA = __builtin_amdgcn_fdot2(kuA.h[1], qu.h[1], pA, false);
      pA = __builtin_amdgcn_fdot2(kuA.h[2], qu.h[2], pA, false);
      pA = __builtin_amdgcn_fdot2(kuA.h[3], qu.h[3], pA, false);
      pB = __builtin_amdgcn_fdot2(kuB.h[0], qu.h[0], 0.f, false);
      pB = __builtin_amdgcn_fdot2(kuB.h[1], qu.h[1], pB, false);
      pB = __builtin_amdgcn_fdot2(kuB.h[2], qu.h[2], pB, false);
      pB = __builtin_amdgcn_fdot2(kuB.h[3], qu.h[3], pB, false);
#else
      pA = 0.f; pB = 0.f;
#pragma unroll
      for (int z = 0; z < 4; z++) {
        pA += (float)kuA.h[z][0] * (float)qu.h[z][0] + (float)kuA.h[z][1] * (float)qu.h[z][1];
        pB += (float)kuB.h[z][0] * (float)qu.h[z][0] + (float)kuB.h[z][1] * (float)qu.h[z][1];
      }
#endif
#pragma unroll
      for (int off = 1; off <= 8; off <<= 1) {
        pA += __shfl_xor(pA, off, 64);
        pB += __shfl_xor(pB, off, 64);
      }
      if (!vA) pA = -INFINITY;
      if (!vB) pB = -INFINITY;

      float pm = fmaxf(pA, pB);
      pm = fmaxf(pm, __shfl_xor(pm, 16));
      pm = fmaxf(pm, __shfl_xor(pm, 32));
      if (pm > m) {
        float al = exp2f(m - pm);          // first trip: exp2(-inf)=0
        l *= al;
#pragma unroll
        for (int z = 0; z < 8; z++) acc[z] *= al;
        m = pm;
      }
      float peA = exp2f(pA - m);
      float peB = exp2f(pB - m);
      float ps = peA + peB;
      ps += __shfl_xor(ps, 16);
      ps += __shfl_xor(ps, 32);
      l += ps;
#pragma unroll
      for (int z = 0; z < 4; z++) {
        acc[2 * z]     = fmaf(peA, (float)vuA.h[z][0], acc[2 * z]);
        acc[2 * z + 1] = fmaf(peA, (float)vuA.h[z][1], acc[2 * z + 1]);
      }
#pragma unroll
      for (int z = 0; z < 4; z++) {
        acc[2 * z]     = fmaf(peB, (float)vuB.h[z][0], acc[2 * z]);
        acc[2 * z + 1] = fmaf(peB, (float)vuB.h[z][1], acc[2 * z + 1]);
      }
    }
  }
  float inv = 0.125f / (l + 1e-16f);      // head-mean folded in
#pragma unroll
  for (int z = 0; z < 8; z++) {
    float a = acc[z] * inv;
    a += __shfl_xor(a, 16);
    a += __shfl_xor(a, 32);
    acc[z] = a;
  }

  if (HPC == 1) {
    if (active && g == 0) {
      float* op = outacc + (size_t)n * CDIM + i * 8;
      if (first) {
        *(float4*)op       = make_float4(acc[0], acc[1], acc[2], acc[3]);
        *(float4*)(op + 4) = make_float4(acc[4], acc[5], acc[6], acc[7]);
      } else {
        float4 o0 = *(float4*)op, o1 = *(float4*)(op + 4);
        *(float4*)op       = make_float4(o0.x + acc[0], o0.y + acc[1], o0.z + acc[2], o0.w + acc[3]);
        *(float4*)(op + 4) = make_float4(o1.x + acc[4], o1.y + acc[5], o1.z + acc[6], o1.w + acc[7]);
      }
    }
  } else {
    __shared__ float sacc[4][128];
    if (g == 0) {
      *(float4*)&sacc[w][i * 8]     = make_float4(acc[0], acc[1], acc[2], acc[3]);
      *(float4*)&sacc[w][i * 8 + 4] = make_float4(acc[4], acc[5], acc[6], acc[7]);
    }
    __syncthreads();
    if (HPC == 4) {
      if (t < 128) {
        float v = sacc[0][t] + sacc[1][t] + sacc[2][t] + sacc[3][t];
        size_t o = (size_t)blockIdx.x * CDIM + t;
        outacc[o] = first ? v : (outacc[o] + v);
      }
    } else {
      int nn = blockIdx.x * 2 + (t >> 7);
      int c = t & 127;
      if (nn < N) {
        float v = sacc[(t >> 7) * 2][c] + sacc[(t >> 7) * 2 + 1][c];
        size_t o = (size_t)nn * CDIM + c;
        outacc[o] = first ? v : (outacc[o] + v);
      }
    }
  }
}

// ---------------- epilogue: beta gate + (residual) + LN + ReLU, 2 nodes/block ----------------
template <int LAYER>
__global__ __launch_bounds__(256) void epilogue_kernel(
    const float* __restrict__ outacc, const u16* __restrict__ xrT,
    const float* __restrict__ Wb, const float* __restrict__ gam, const float* __restrict__ bet,
    const u16* __restrict__ res,
    u16* __restrict__ hout, float* __restrict__ houtf, int N)
{
  int t = threadIdx.x;
  int local = t >> 7, c = t & 127, w = t >> 6;
  int n = blockIdx.x * 2 + local;
  bool act = n < N;
  __shared__ float sred[8];
  __shared__ float smv[2][3];

  float oc = 0.f, xc = 0.f;
  if (act) {
    oc = outacc[(size_t)n * CDIM + c];
    xc = b2f(xrT[((size_t)(c >> 6) * N + n) * 64 + (c & 63)]);
  }
  float pb = oc * Wb[c] + xc * Wb[CDIM + c] + (oc - xc) * Wb[2 * CDIM + c];
#pragma unroll
  for (int off = 32; off; off >>= 1) pb += __shfl_down(pb, off, 64);
  if ((t & 63) == 0) sred[w] = pb;
  __syncthreads();
  if (t == 0)   smv[0][0] = 1.f / (1.f + __expf(-(sred[0] + sred[1])));
  if (t == 128) smv[1][0] = 1.f / (1.f + __expf(-(sred[2] + sred[3])));
  __syncthreads();
  float beta = smv[local][0];
  float val = beta * xc + (1.f - beta) * oc;
  if (LAYER == 1 && act) val += b2f(res[(size_t)n * CDIM + c]);

  float s1 = val, s2 = val * val;
#pragma unroll
  for (int off = 32; off; off >>= 1) {
    s1 += __shfl_down(s1, off, 64);
    s2 += __shfl_down(s2, off, 64);
  }
  __syncthreads();
  if ((t & 63) == 0) { sred[w * 2] = s1; sred[w * 2 + 1] = s2; }
  __syncthreads();
  if (t == 0) {
    float S1 = sred[0] + sred[2], S2 = sred[1] + sred[3];
    float mu = S1 * (1.f / CDIM);
    float var = fmaxf(S2 * (1.f / CDIM) - mu * mu, 0.f);
    smv[0][1] = mu; smv[0][2] = 1.f / sqrtf(var + 1e-5f);
  }
  if (t == 128) {
    float S1 = sred[4] + sred[6], S2 = sred[5] + sred[7];
    float mu = S1 * (1.f / CDIM);
    float var = fmaxf(S2 * (1.f / CDIM) - mu * mu, 0.f);
    smv[1][1] = mu; smv[1][2] = 1.f / sqrtf(var + 1e-5f);
  }
  __syncthreads();
  if (act) {
    float y = (val - smv[local][1]) * smv[local][2] * gam[c] + bet[c];
    y = fmaxf(y, 0.f);
    if (LAYER == 0) hout[(size_t)n * CDIM + c] = f2b(y);
    else            houtf[(size_t)n * CDIM + c] = y;
  }
}

// ---------------- fused pool + classifier: one block per graph ----------------
__global__ __launch_bounds__(256) void classifier_kernel(
    const float* __restrict__ hf, const int* __restrict__ gb,
    const float* __restrict__ Wc1, const float* __restrict__ bc1,
    const float* __restrict__ Wc2, const float* __restrict__ bc2,
    float* __restrict__ out)
{
  int g = blockIdx.x, t = threadIdx.x;
  int half = t >> 7, c = t & 127;
  int s = gb[g], e = gb[g + 1];
  float acc = 0.f;
  for (int n = s + half; n < e; n += 2) acc += hf[(size_t)n * CDIM + c];
  __shared__ float sb[2][128];
  __shared__ float sp[128], sz[64];
  sb[half][c] = acc;
  __syncthreads();
  float cg = fmaxf((float)(e - s), 1.f);
  if (t < 128) sp[t] = (sb[0][t] + sb[1][t]) / cg;
  __syncthreads();
  if (t < 64) {
    float a = bc1[t];
    for (int cc = 0; cc < 128; cc++) a += sp[cc] * Wc1[cc * 64 + t];
    sz[t] = fmaxf(a, 0.f);
  }
  __syncthreads();
  if (t < 64) {
    float pbv = sz[t] * Wc2[t];
    for (int off = 32; off; off >>= 1) pbv += __shfl_down(pbv, off, 64);
    if (t == 0) out[g] = pbv + bc2[0];
  }
}

// ---------------- host orchestration ----------------
extern "C" void kernel_launch(void* const* d_in, const int* in_sizes, int n_in,
                              void* d_out, int out_size, void* d_ws, size_t ws_size,
                              hipStream_t stream)
{
  if (n_in != 30) return;

  const int N = in_sizes[0];
  const int E = in_sizes[1] / 2;

  const int* x     = (const int*)d_in[0];
  const int* ei    = (const int*)d_in[1];
  const int* batch = (const int*)d_in[2];
  const float* emb = (const float*)d_in[3];
  const float* Wq0 = (const float*)d_in[4];  const float* bq0 = (const float*)d_in[5];
  const float* Wk0 = (const float*)d_in[6];  const float* bk0 = (const float*)d_in[7];
  const float* Wv0 = (const float*)d_in[8];  const float* bv0 = (const float*)d_in[9];
  const float* Ws0 = (const float*)d_in[10]; const float* bs0 = (const float*)d_in[11];
  const float* Wb0 = (const float*)d_in[12]; const float* g0  = (const float*)d_in[13]; const float* be0 = (const float*)d_in[14];
  const float* Wq1 = (const float*)d_in[15]; const float* bq1 = (const float*)d_in[16];
  const float* Wk1 = (const float*)d_in[17]; const float* bk1 = (const float*)d_in[18];
  const float* Wv1 = (const float*)d_in[19]; const float* bv1 = (const float*)d_in[20];
  const float* Ws1 = (const float*)d_in[21]; const float* bs1 = (const float*)d_in[22];
  const float* Wb1 = (const float*)d_in[23]; const float* g1  = (const float*)d_in[24]; const float* be1 = (const float*)d_in[25];
  const float* Wc1 = (const float*)d_in[26]; const float* bc1 = (const float*)d_in[27];
  const float* Wc2 = (const float*)d_in[28]; const float* bc2 = (const float*)d_in[29];

  auto rnd = [](size_t b) { return (b + 511) & ~(size_t)511; };
  size_t fixedBytes =
      rnd((size_t)N * CDIM * 4) +
      rnd((size_t)N * EMBD * 2) +
      rnd((size_t)N * CDIM * 2) * 2 +
      rnd((size_t)3 * HC * EMBD * 2) +
      rnd((size_t)3 * HC * CDIM * 2) +
      rnd((size_t)3 * HC * 4) * 2 +
      rnd((size_t)CDIM * EMBD * 2) +
      rnd((size_t)CDIM * CDIM * 2) +
      rnd((size_t)N * 4) * 2 +
      rnd((size_t)(N + 1) * 4) +
      rnd((size_t)E * 4) +
      rnd(256 * 4) +
      rnd(65 * 4);
  int hpc = 1;
  if (ws_size >= fixedBytes + rnd((size_t)N * 4 * 384 * 2)) hpc = 4;
  else if (ws_size >= fixedBytes + rnd((size_t)N * 2 * 384 * 2)) hpc = 2;
  const int chunkCols = hpc * 384;
  const int nchunks = HEADS / hpc;
  const int qkvTiles = chunkCols / 64;

  char* ws = (char*)d_ws;
  size_t off = 0;
  auto alloc = [&](size_t bytes) -> void* {
    void* p = ws + off;
    off += (bytes + 511) & ~(size_t)511;
    return p;
  };
  u16*   qkvc  = (u16*)  alloc((size_t)N * chunkCols * 2);  // tiled f16 per chunk
  float* outacc= (float*)alloc((size_t)N * CDIM * 4);
  u16*   h0    = (u16*)  alloc((size_t)N * EMBD * 2);       // layer-0 A; reused as f32 final features
  u16*   h1    = (u16*)  alloc((size_t)N * CDIM * 2);
  u16*   xrb   = (u16*)  alloc((size_t)N * CDIM * 2);       // tiled (2 tiles of 64), bf16
  u16*   WT0   = (u16*)  alloc((size_t)3 * HC * EMBD * 2);  // fragment-swizzled
  u16*   WT1   = (u16*)  alloc((size_t)3 * HC * CDIM * 2);
  float* bT0   = (float*)alloc((size_t)3 * HC * 4);
  float* bT1   = (float*)alloc((size_t)3 * HC * 4);
  u16*   WsT0  = (u16*)  alloc((size_t)CDIM * EMBD * 2);    // fragment-swizzled
  u16*   WsT1  = (u16*)  alloc((size_t)CDIM * CDIM * 2);
  int*   deg   = (int*)  alloc((size_t)N * 4);
  int*   fill  = (int*)  alloc((size_t)N * 4);
  int*   rowp  = (int*)  alloc((size_t)(N + 1) * 4);
  int*   colb  = (int*)  alloc((size_t)E * 4);
  int*   bsum  = (int*)  alloc(256 * 4);
  int*   gb    = (int*)  alloc(65 * 4);

  hipMemsetAsync(deg, 0, (size_t)N * 4, stream);
  hipMemsetAsync(fill, 0, (size_t)N * 4, stream);

  // prep
  embed_kernel<<<(N * 64 + 255) / 256, 256, 0, stream>>>(x, emb, h0, N);
  { dim3 gT(3 * HC / 128, EMBD / 64);
    build_qkvT_swz<<<gT, 256, 0, stream>>>(Wq0, Wk0, Wv0, WT0, EMBD, hpc); }
  { dim3 gT(3 * HC / 128, CDIM / 64);
    build_qkvT_swz<<<gT, 256, 0, stream>>>(Wq1, Wk1, Wv1, WT1, CDIM, hpc); }
  build_qkvb<<<(3 * HC + 255) / 256, 256, 0, stream>>>(bq0, bk0, bv0, bT0, hpc);
  build_qkvb<<<(3 * HC + 255) / 256, 256, 0, stream>>>(bq1, bk1, bv1, bT1, hpc);
  { dim3 gT(2, EMBD / 32);
    build_WsT_swz<<<gT, 256, 0, stream>>>(Ws0, WsT0, EMBD); }
  { dim3 gT(2, CDIM / 32);
    build_WsT_swz<<<gT, 256, 0, stream>>>(Ws1, WsT1, CDIM); }

  // CSR by dst + graph bounds
  int nb = (N + 255) / 256;
  deg_kernel<<<(E + 255) / 256, 256, 0, stream>>>(ei, deg, E);
  scan1_kernel<<<nb, 256, 0, stream>>>(deg, rowp, bsum, N);
  scan2_kernel<<<1, 256, 0, stream>>>(bsum, nb);
  scan3_kernel<<<nb, 256, 0, stream>>>(rowp, bsum, N);
  scatter_kernel<<<(E + 255) / 256, 256, 0, stream>>>(ei, rowp, fill, colb, E);
  gb_kernel<<<1, 128, 0, stream>>>(batch, gb, N);

  int rowStrips = (N + 63) / 64;
  float* hfinal = (float*)h0;
  int epiBlocks = (N + 1) / 2;

  if (hpc == 4) {
    // ---- fast path: 2 fused GEMMs + 2 attn + 1 epilogue per layer ----
    for (int layer = 0; layer < 2; layer++) {
      const u16* Ain   = (layer == 0) ? h0 : h1;
      const u16* WT    = (layer == 0) ? WT0 : WT1;
      const float* bT  = (layer == 0) ? bT0 : bT1;
      const u16* WsT   = (layer == 0) ? WsT0 : WsT1;
      const float* bs  = (layer == 0) ? bs0 : bs1;
      const float* Wb  = (layer == 0) ? Wb0 : Wb1;
      const float* gam = (layer == 0) ? g0 : g1;
      const float* bet = (layer == 0) ? be0 : be1;
      int K = (layer == 0) ? EMBD : CDIM;

      int nT0 = qkvTiles + 2;                      // chunk-0 + 2 XR tiles
      dim3 gG0((nT0 + 3) / 4, rowStrips);
      dim3 gG1((qkvTiles + 3) / 4, rowStrips);
      if (K == EMBD)
        gemm_lds<EMBD><<<gG0, 256, 0, stream>>>(Ain, WT, WsT, 0, qkvTiles, bT, bs, qkvc, xrb, N, nT0);
      else
        gemm_lds<CDIM><<<gG0, 256, 0, stream>>>(Ain, WT, WsT, 0, qkvTiles, bT, bs, qkvc, xrb, N, nT0);
      attn_chunk_kernel<4><<<N, 256, 0, stream>>>(qkvc, rowp, colb, outacc, N, 1);
      if (K == EMBD)
        gemm_lds<EMBD><<<gG1, 256, 0, stream>>>(Ain, WT, WsT, qkvTiles, 1 << 30, bT, bs, qkvc, xrb, N, qkvTiles);
      else
        gemm_lds<CDIM><<<gG1, 256, 0, stream>>>(Ain, WT, WsT, qkvTiles, 1 << 30, bT, bs, qkvc, xrb, N, qkvTiles);
      attn_chunk_kernel<4><<<N, 256, 0, stream>>>(qkvc, rowp, colb, outacc, N, 0);
      if (layer == 0)
        epilogue_kernel<0><<<epiBlocks, 256, 0, stream>>>(outacc, xrb, Wb, gam, bet,
                                                          (const u16*)nullptr, h1, (float*)nullptr, N);
      else
        epilogue_kernel<1><<<epiBlocks, 256, 0, stream>>>(outacc, xrb, Wb, gam, bet,
                                                          h1, (u16*)nullptr, hfinal, N);
    }
  } else {
    // ---- legacy fallback ----
    int attnBlocks = (hpc == 2) ? (N + 1) / 2 : (N + 3) / 4;
    for (int layer = 0; layer < 2; layer++) {
      const u16* Ain   = (layer == 0) ? h0 : h1;
      const u16* WT    = (layer == 0) ? WT0 : WT1;
      const float* bT  = (layer == 0) ? bT0 : bT1;
      const u16* WsT   = (layer == 0) ? WsT0 : WsT1;
      const float* bs  = (layer == 0) ? bs0 : bs1;
      const float* Wb  = (layer == 0) ? Wb0 : Wb1;
      const float* gam = (layer == 0) ? g0 : g1;
      const float* bet = (layer == 0) ? be0 : be1;
      int K = (layer == 0) ? EMBD : CDIM;

      dim3 gXR(1, rowStrips);
      dim3 gQKV((qkvTiles + 3) / 4, rowStrips);
      if (K == EMBD) gemm_lds<EMBD><<<gXR, 256, 0, stream>>>(Ain, WT, WsT, 0, 0, bT, bs, qkvc, xrb, N, 2);
      else           gemm_lds<CDIM><<<gXR, 256, 0, stream>>>(Ain, WT, WsT, 0, 0, bT, bs, qkvc, xrb, N, 2);
      for (int c = 0; c < nchunks; c++) {
        int col0tile = c * qkvTiles;
        if (K == EMBD)
          gemm_lds<EMBD><<<gQKV, 256, 0, stream>>>(Ain, WT, WsT, col0tile, 1 << 30, bT, bs, qkvc, xrb, N, qkvTiles);
        else
          gemm_lds<CDIM><<<gQKV, 256, 0, stream>>>(Ain, WT, WsT, col0tile, 1 << 30, bT, bs, qkvc, xrb, N, qkvTiles);
        int first = (c == 0) ? 1 : 0;
        if (hpc == 2)
          attn_chunk_kernel<2><<<attnBlocks, 256, 0, stream>>>(qkvc, rowp, colb, outacc, N, first);
        else
          attn_chunk_kernel<1><<<attnBlocks, 256, 0, stream>>>(qkvc, rowp, colb, outacc, N, first);
      }
      if (layer == 0)
        epilogue_kernel<0><<<epiBlocks, 256, 0, stream>>>(outacc, xrb, Wb, gam, bet,
                                                          (const u16*)nullptr, h1, (float*)nullptr, N);
      else
        epilogue_kernel<1><<<epiBlocks, 256, 0, stream>>>(outacc, xrb, Wb, gam, bet,
                                                          h1, (u16*)nullptr, hfinal, N);
    }
  }

  classifier_kernel<<<NGRAPH, 256, 0, stream>>>(hfinal, gb, Wc1, bc1, Wc2, bc2,
                                                (float*)d_out);
}

// Round 14
// 1073.157 us; speedup vs baseline: 1.0378x; 1.0378x over previous
//
#include <hip/hip_runtime.h>
#include <hip/hip_fp16.h>
#include <math.h>

#define HEADS 8
#define CDIM 128
#define HC 1024
#define EMBD 256
#define NGRAPH 64
#define QSCALE2 0.12751744f             // (1/sqrt(128)) * log2(e): exp2-domain logits

typedef unsigned short u16;
typedef short s8v __attribute__((ext_vector_type(8)));
typedef float f4v __attribute__((ext_vector_type(4)));
typedef _Float16 h2v __attribute__((ext_vector_type(2)));

__device__ __forceinline__ float b2f(u16 u) {
  union { unsigned int i; float f; } v; v.i = ((unsigned int)u) << 16; return v.f;
}
__device__ __forceinline__ u16 f2b(float f) {
  union { float f; unsigned int i; } v; v.f = f;
  unsigned int i = v.i;
  unsigned int r = (i + 0x7FFFu + ((i >> 16) & 1u)) >> 16;
  return (u16)r;
}
__device__ __forceinline__ u16 f2h(float f) {
  __half h = __float2half(f);
  return *(u16*)&h;
}

union U4H { uint4 u; h2v h[4]; };

// ---------------- embedding gather + f32->bf16 ----------------
__global__ __launch_bounds__(256) void embed_kernel(
    const int* __restrict__ x, const float* __restrict__ emb,
    u16* __restrict__ h0, int N)
{
  int idx = blockIdx.x * 256 + threadIdx.x;
  if (idx >= N * (EMBD / 4)) return;
  int n = idx >> 6;
  int j = (idx & 63) * 4;
  int vid = x[n];
  float4 f = *(const float4*)&emb[(size_t)vid * EMBD + j];
  ushort4 u;
  u.x = f2b(f.x); u.y = f2b(f.y); u.z = f2b(f.z); u.w = f2b(f.w);
  *(ushort4*)&h0[(size_t)n * EMBD + j] = u;
}

// ---------------- Ws -> fragment-swizzled bf16 B ----------------
__global__ __launch_bounds__(256) void build_WsT_swz(
    const float* __restrict__ in, u16* __restrict__ out, int K)
{
  const int KS = K / 32;
  int nt = blockIdx.x;
  int ks = blockIdx.y;
  int t = threadIdx.x;
  int lane = t & 63, ni = t >> 6;
  int q4 = lane >> 4, cn = lane & 15;
  int colL = nt * 64 + ni * 16 + cn;
  int kbase = ks * 32 + q4 * 8;
  u16 tmp[8];
#pragma unroll
  for (int e8 = 0; e8 < 8; e8++) tmp[e8] = f2b(in[(size_t)(kbase + e8) * CDIM + colL]);
  size_t base = ((((size_t)nt * KS + ks) * 4 + ni) * 64 + lane) * 8;
  *(uint4*)&out[base] = *(uint4*)tmp;
}

// ---------------- chunked qkv^T weights -> fragment-swizzled bf16 (QSCALE2 in q) ----------------
__global__ __launch_bounds__(256) void build_qkvT_swz(
    const float* __restrict__ Wq, const float* __restrict__ Wk, const float* __restrict__ Wv,
    u16* __restrict__ WT, int K, int hpc)
{
  __shared__ u16 tile[64][130];
  const int KS = K / 32;
  int rg0 = blockIdx.x * 128;
  int kk0 = blockIdx.y * 64;
  int chunkCols = hpc * 384;
  int chunk = rg0 / chunkCols;
  int within = rg0 - chunk * chunkCols;
  int head = chunk * hpc + within / 384;
  int sub = within % 384;
  int sect = sub >> 7;
  const float* W = (sect == 0) ? Wq : (sect == 1 ? Wk : Wv);
  float scale = (sect == 0) ? QSCALE2 : 1.0f;
  int cc0 = head * CDIM;
  int t = threadIdx.x;
  int ci = t & 127, k2 = t >> 7;
#pragma unroll
  for (int ii = 0; ii < 32; ii++) {
    int ki = k2 + ii * 2;
    tile[ki][ci] = f2b(W[(size_t)(kk0 + ki) * HC + cc0 + ci] * scale);
  }
  __syncthreads();

  int lane = t & 63, ni = t >> 6;
  int q4 = lane >> 4, cn = lane & 15;
  int ntBase = rg0 >> 6;
#pragma unroll
  for (int ntd = 0; ntd < 2; ntd++) {
#pragma unroll
    for (int ksd = 0; ksd < 2; ksd++) {
      int colL = ntd * 64 + ni * 16 + cn;
      int kL = ksd * 32 + q4 * 8;
      u16 tmp[8];
#pragma unroll
      for (int e8 = 0; e8 < 8; e8++) tmp[e8] = tile[kL + e8][colL];
      size_t base = ((((size_t)(ntBase + ntd) * KS + (kk0 >> 5) + ksd) * 4 + ni) * 64 + lane) * 8;
      *(uint4*)&WT[base] = *(uint4*)tmp;
    }
  }
}
__global__ __launch_bounds__(256) void build_qkvb(
    const float* __restrict__ bq, const float* __restrict__ bk, const float* __restrict__ bv,
    float* __restrict__ bT, int hpc)
{
  int rg = blockIdx.x * 256 + threadIdx.x;
  if (rg >= 3 * HC) return;
  int chunkCols = hpc * 384;
  int chunk = rg / chunkCols;
  int within = rg - chunk * chunkCols;
  int head = chunk * hpc + within / 384;
  int sub = within % 384;
  int sect = sub >> 7;
  int cc = head * CDIM + (sub & 127);
  bT[rg] = (sect == 0) ? bq[cc] * QSCALE2 : (sect == 1 ? bk[cc] : bv[cc]);
}

// ---------------- CSR build ----------------
__global__ __launch_bounds__(256) void deg_kernel(const int* __restrict__ ei, int* __restrict__ deg, int E) {
  int e = blockIdx.x * 256 + threadIdx.x;
  if (e < E) atomicAdd(&deg[ei[E + e]], 1);
}
__global__ __launch_bounds__(256) void scan1_kernel(const int* __restrict__ deg, int* __restrict__ row_ptr,
                                                    int* __restrict__ bsum, int N) {
  __shared__ int sb[256];
  int t = threadIdx.x, idx = blockIdx.x * 256 + t;
  int x = (idx < N) ? deg[idx] : 0;
  sb[t] = x; __syncthreads();
  for (int off = 1; off < 256; off <<= 1) {
    int y = (t >= off) ? sb[t - off] : 0;
    __syncthreads(); sb[t] += y; __syncthreads();
  }
  if (idx < N) row_ptr[idx + 1] = sb[t];
  if (t == 255) bsum[blockIdx.x] = sb[255];
  if (idx == 0) row_ptr[0] = 0;
}
__global__ __launch_bounds__(256) void scan2_kernel(int* __restrict__ bsum, int B) {
  __shared__ int sb[256];
  int t = threadIdx.x;
  int x = (t < B) ? bsum[t] : 0;
  sb[t] = x; __syncthreads();
  for (int off = 1; off < 256; off <<= 1) {
    int y = (t >= off) ? sb[t - off] : 0;
    __syncthreads(); sb[t] += y; __syncthreads();
  }
  if (t < B) bsum[t] = sb[t] - x;   // exclusive
}
__global__ __launch_bounds__(256) void scan3_kernel(int* __restrict__ row_ptr, const int* __restrict__ bsum, int N) {
  int idx = blockIdx.x * 256 + threadIdx.x;
  if (idx < N) row_ptr[idx + 1] += bsum[idx >> 8];
}
__global__ __launch_bounds__(256) void scatter_kernel(const int* __restrict__ ei,
                                                      const int* __restrict__ row_ptr,
                                                      int* __restrict__ fill, int* __restrict__ col, int E) {
  int e = blockIdx.x * 256 + threadIdx.x;
  if (e >= E) return;
  int d = ei[E + e];
  int pos = row_ptr[d] + atomicAdd(&fill[d], 1);
  col[pos] = ei[e];
}
__global__ void gb_kernel(const int* __restrict__ batch, int* __restrict__ gb, int N) {
  int g = threadIdx.x;
  if (g > NGRAPH) return;
  int lo = 0, hi = N;
  while (lo < hi) { int mid = (lo + hi) >> 1; if (batch[mid] < g) lo = mid + 1; else hi = mid; }
  gb[g] = lo;
}

// ---------------- GEMM: A in LDS once; B fragment-swizzled from L2; XCD-swizzled grid ----------------
// 1D grid. All tile-groups of one 64-row strip share (blockIdx % 8) -> same XCD -> A fetched once.
template <int K>
__global__ __launch_bounds__(256, 3) void gemm_lds(
    const u16* __restrict__ A, const u16* __restrict__ Bq, const u16* __restrict__ Bx,
    int col0tile, int xrTile0,
    const float* __restrict__ biasQ, const float* __restrict__ biasX,
    u16* __restrict__ outQ, u16* __restrict__ outX,
    int M, int nTiles, int rowStrips, int nGroups)
{
  const int LDK = K + 8;
  const int KS = K / 32;
  __shared__ __align__(16) u16 As[64 * LDK];
  int B = blockIdx.x;
  int c8 = B & 7, kk = B >> 3;
  int tg = kk % nGroups;
  int s  = (kk / nGroups) * 8 + c8;
  if (s >= rowStrips) return;
  int t = threadIdx.x, lane = t & 63, w = t >> 6;
  int q4 = lane >> 4, cn = lane & 15;
  int m0 = s * 64;
  int ntL = tg * 4 + w;
  bool wActive = ntL < nTiles;
  int ntG = col0tile + ntL;
  bool isXr = ntG >= xrTile0;

  if (m0 + 64 <= M) {
    const u16* Ablk = A + (size_t)m0 * K;
#pragma unroll
    for (int ii = 0; ii < K / 32; ii++) {
      int g = (ii * 256 + t) * 8;
      int r = g / K, c = g - r * K;
      *(uint4*)&As[r * LDK + c] = *(const uint4*)(Ablk + g);
    }
  } else {
#pragma unroll
    for (int ii = 0; ii < K / 32; ii++) {
      int g = (ii * 256 + t) * 8;
      int r = g / K, c = g - r * K;
      int gr = m0 + r; if (gr >= M) gr = M - 1;
      *(uint4*)&As[r * LDK + c] = *(const uint4*)(A + (size_t)gr * K + c);
    }
  }
  __syncthreads();

  if (!wActive) return;

  f4v acc[4][4] = {};
  const u16* bb = isXr
      ? Bx + ((size_t)(ntG - xrTile0) * KS * 4) * 512 + lane * 8
      : Bq + ((size_t)ntG * KS * 4) * 512 + lane * 8;
#pragma unroll
  for (int ks = 0; ks < KS; ks++) {
    s8v bf[4], af[4];
#pragma unroll
    for (int ni = 0; ni < 4; ni++)
      bf[ni] = *(const s8v*)(bb + ((size_t)ks * 4 + ni) * 512);
#pragma unroll
    for (int mi = 0; mi < 4; mi++)
      af[mi] = *(const s8v*)&As[(mi * 16 + cn) * LDK + ks * 32 + q4 * 8];
#pragma unroll
    for (int mi = 0; mi < 4; mi++)
#pragma unroll
      for (int ni = 0; ni < 4; ni++)
        acc[mi][ni] = __builtin_amdgcn_mfma_f32_16x16x32_bf16(af[mi], bf[ni], acc[mi][ni], 0, 0, 0);
  }

  u16* obase = isXr ? outX + (size_t)(ntG - xrTile0) * M * 64
                    : outQ + (size_t)ntL * M * 64;
  float bv[4];
#pragma unroll
  for (int ni = 0; ni < 4; ni++)
    bv[ni] = isXr ? biasX[(ntG - xrTile0) * 64 + ni * 16 + cn]
                  : biasQ[ntG * 64 + ni * 16 + cn];
#pragma unroll
  for (int mi = 0; mi < 4; mi++) {
#pragma unroll
    for (int j = 0; j < 4; j++) {
      int gm = m0 + mi * 16 + q4 * 4 + j;
      if (gm < M) {
#pragma unroll
        for (int ni = 0; ni < 4; ni++) {
          float val = acc[mi][ni][j] + bv[ni];
          obase[(size_t)gm * 64 + ni * 16 + cn] = isXr ? f2b(val) : f2h(val);
        }
      }
    }
  }
}

// ---------------- attention chunk: f16 qkv, 8 edges/trip, 16 lanes/edge, merged rescale ----------------
template <int HPC>
__global__ __launch_bounds__(256) void attn_chunk_kernel(
    const u16* __restrict__ qkv,
    const int* __restrict__ row_ptr, const int* __restrict__ col,
    float* __restrict__ outacc, int N, int first)
{
  int t = threadIdx.x;
  int w = t >> 6, lane = t & 63;
  int g = lane >> 4, i = lane & 15;     // edge group 0..3, channel sub (8 ch/lane)
  int n, j;
  if (HPC == 4)      { n = blockIdx.x;                 j = w; }
  else if (HPC == 2) { n = blockIdx.x * 2 + (w >> 1);  j = w & 1; }
  else               { n = blockIdx.x * 4 + w;         j = 0; }
  bool active = (HPC == 4) ? true : (n < N);

  int itile = i >> 3, ioff = (i & 7) * 8;
  const u16* qb = qkv + (size_t)(j * 6 + 0 + itile) * N * 64 + ioff;
  const u16* kb = qkv + (size_t)(j * 6 + 2 + itile) * N * 64 + ioff;
  const u16* vb = qkv + (size_t)(j * 6 + 4 + itile) * N * 64 + ioff;

  float acc[8] = {};
  float m = -INFINITY, l = 0.f;
  if (active) {
    U4H qu; qu.u = *(const uint4*)(qb + (size_t)n * 64);
    int e0 = row_ptr[n], e1 = row_ptr[n + 1];
    for (int eb = e0; eb < e1; eb += 8) {
      int egA = eb + g, egB = eb + 4 + g;
      bool vA = egA < e1, vB = egB < e1;
      int sA = col[vA ? egA : e1 - 1];
      int sB = col[vB ? egB : e1 - 1];
      U4H kuA, vuA, kuB, vuB;
      kuA.u = *(const uint4*)(kb + (size_t)sA * 64);
      kuB.u = *(const uint4*)(kb + (size_t)sB * 64);
      vuA.u = *(const uint4*)(vb + (size_t)sA * 64);
      vuB.u = *(const uint4*)(vb + (size_t)sB * 64);

      float pA, pB;
#if defined(__has_builtin) && __has_builtin(__builtin_amdgcn_fdot2)
      pA = __builtin_amdgcn_fdot2(kuA.h[0], qu.h[0], 0.f, false);
      pA = __builtin_amdgcn_fdot2(kuA.h[1], qu.h[1], pA, false);
      pA = __builtin_amdgcn_fdot2(kuA.h[2], qu.h[2], pA, false);
      pA = __builtin_amdgcn_fdot2(kuA.h[3], qu.h[3], pA, false);
      pB = __builtin_amdgcn_fdot2(kuB.h[0], qu.h[0], 0.f, false);
      pB = __builtin_amdgcn_fdot2(kuB.h[1], qu.h[1], pB, false);
      pB = __builtin_amdgcn_fdot2(kuB.h[2], qu.h[2], pB, false);
      pB = __builtin_amdgcn_fdot2(kuB.h[3], qu.h[3], pB, false);
#else
      pA = 0.f; pB = 0.f;
#pragma unroll
      for (int z = 0; z < 4; z++) {
        pA += (float)kuA.h[z][0] * (float)qu.h[z][0] + (float)kuA.h[z][1] * (float)qu.h[z][1];
        pB += (float)kuB.h[z][0] * (float)qu.h[z][0] + (float)kuB.h[z][1] * (float)qu.h[z][1];
      }
#endif
#pragma unroll
      for (int off = 1; off <= 8; off <<= 1) {
        pA += __shfl_xor(pA, off, 64);
        pB += __shfl_xor(pB, off, 64);
      }
      if (!vA) pA = -INFINITY;
      if (!vB) pB = -INFINITY;

      float pm = fmaxf(pA, pB);
      pm = fmaxf(pm, __shfl_xor(pm, 16));
      pm = fmaxf(pm, __shfl_xor(pm, 32));
      if (pm > m) {
        float al = exp2f(m - pm);          // first trip: exp2(-inf)=0
        l *= al;
#pragma unroll
        for (int z = 0; z < 8; z++) acc[z] *= al;
        m = pm;
      }
      float peA = exp2f(pA - m);
      float peB = exp2f(pB - m);
      float ps = peA + peB;
      ps += __shfl_xor(ps, 16);
      ps += __shfl_xor(ps, 32);
      l += ps;
#pragma unroll
      for (int z = 0; z < 4; z++) {
        acc[2 * z]     = fmaf(peA, (float)vuA.h[z][0], acc[2 * z]);
        acc[2 * z + 1] = fmaf(peA, (float)vuA.h[z][1], acc[2 * z + 1]);
      }
#pragma unroll
      for (int z = 0; z < 4; z++) {
        acc[2 * z]     = fmaf(peB, (float)vuB.h[z][0], acc[2 * z]);
        acc[2 * z + 1] = fmaf(peB, (float)vuB.h[z][1], acc[2 * z + 1]);
      }
    }
  }
  float inv = 0.125f / (l + 1e-16f);      // head-mean folded in
#pragma unroll
  for (int z = 0; z < 8; z++) {
    float a = acc[z] * inv;
    a += __shfl_xor(a, 16);
    a += __shfl_xor(a, 32);
    acc[z] = a;
  }

  if (HPC == 1) {
    if (active && g == 0) {
      float* op = outacc + (size_t)n * CDIM + i * 8;
      if (first) {
        *(float4*)op       = make_float4(acc[0], acc[1], acc[2], acc[3]);
        *(float4*)(op + 4) = make_float4(acc[4], acc[5], acc[6], acc[7]);
      } else {
        float4 o0 = *(float4*)op, o1 = *(float4*)(op + 4);
        *(float4*)op       = make_float4(o0.x + acc[0], o0.y + acc[1], o0.z + acc[2], o0.w + acc[3]);
        *(float4*)(op + 4) = make_float4(o1.x + acc[4], o1.y + acc[5], o1.z + acc[6], o1.w + acc[7]);
      }
    }
  } else {
    __shared__ float sacc[4][128];
    if (g == 0) {
      *(float4*)&sacc[w][i * 8]     = make_float4(acc[0], acc[1], acc[2], acc[3]);
      *(float4*)&sacc[w][i * 8 + 4] = make_float4(acc[4], acc[5], acc[6], acc[7]);
    }
    __syncthreads();
    if (HPC == 4) {
      if (t < 128) {
        float v = sacc[0][t] + sacc[1][t] + sacc[2][t] + sacc[3][t];
        size_t o = (size_t)blockIdx.x * CDIM + t;
        outacc[o] = first ? v : (outacc[o] + v);
      }
    } else {
      int nn = blockIdx.x * 2 + (t >> 7);
      int c = t & 127;
      if (nn < N) {
        float v = sacc[(t >> 7) * 2][c] + sacc[(t >> 7) * 2 + 1][c];
        size_t o = (size_t)nn * CDIM + c;
        outacc[o] = first ? v : (outacc[o] + v);
      }
    }
  }
}

// ---------------- epilogue: beta gate + (residual) + LN + ReLU, 2 nodes/block ----------------
template <int LAYER>
__global__ __launch_bounds__(256) void epilogue_kernel(
    const float* __restrict__ outacc, const u16* __restrict__ xrT,
    const float* __restrict__ Wb, const float* __restrict__ gam, const float* __restrict__ bet,
    const u16* __restrict__ res,
    u16* __restrict__ hout, float* __restrict__ houtf, int N)
{
  int t = threadIdx.x;
  int local = t >> 7, c = t & 127, w = t >> 6;
  int n = blockIdx.x * 2 + local;
  bool act = n < N;
  __shared__ float sred[8];
  __shared__ float smv[2][3];

  float oc = 0.f, xc = 0.f;
  if (act) {
    oc = outacc[(size_t)n * CDIM + c];
    xc = b2f(xrT[((size_t)(c >> 6) * N + n) * 64 + (c & 63)]);
  }
  float pb = oc * Wb[c] + xc * Wb[CDIM + c] + (oc - xc) * Wb[2 * CDIM + c];
#pragma unroll
  for (int off = 32; off; off >>= 1) pb += __shfl_down(pb, off, 64);
  if ((t & 63) == 0) sred[w] = pb;
  __syncthreads();
  if (t == 0)   smv[0][0] = 1.f / (1.f + __expf(-(sred[0] + sred[1])));
  if (t == 128) smv[1][0] = 1.f / (1.f + __expf(-(sred[2] + sred[3])));
  __syncthreads();
  float beta = smv[local][0];
  float val = beta * xc + (1.f - beta) * oc;
  if (LAYER == 1 && act) val += b2f(res[(size_t)n * CDIM + c]);

  float s1 = val, s2 = val * val;
#pragma unroll
  for (int off = 32; off; off >>= 1) {
    s1 += __shfl_down(s1, off, 64);
    s2 += __shfl_down(s2, off, 64);
  }
  __syncthreads();
  if ((t & 63) == 0) { sred[w * 2] = s1; sred[w * 2 + 1] = s2; }
  __syncthreads();
  if (t == 0) {
    float S1 = sred[0] + sred[2], S2 = sred[1] + sred[3];
    float mu = S1 * (1.f / CDIM);
    float var = fmaxf(S2 * (1.f / CDIM) - mu * mu, 0.f);
    smv[0][1] = mu; smv[0][2] = 1.f / sqrtf(var + 1e-5f);
  }
  if (t == 128) {
    float S1 = sred[4] + sred[6], S2 = sred[5] + sred[7];
    float mu = S1 * (1.f / CDIM);
    float var = fmaxf(S2 * (1.f / CDIM) - mu * mu, 0.f);
    smv[1][1] = mu; smv[1][2] = 1.f / sqrtf(var + 1e-5f);
  }
  __syncthreads();
  if (act) {
    float y = (val - smv[local][1]) * smv[local][2] * gam[c] + bet[c];
    y = fmaxf(y, 0.f);
    if (LAYER == 0) hout[(size_t)n * CDIM + c] = f2b(y);
    else            houtf[(size_t)n * CDIM + c] = y;
  }
}

// ---------------- fused pool + classifier: one block per graph ----------------
__global__ __launch_bounds__(256) void classifier_kernel(
    const float* __restrict__ hf, const int* __restrict__ gb,
    const float* __restrict__ Wc1, const float* __restrict__ bc1,
    const float* __restrict__ Wc2, const float* __restrict__ bc2,
    float* __restrict__ out)
{
  int g = blockIdx.x, t = threadIdx.x;
  int half = t >> 7, c = t & 127;
  int s = gb[g], e = gb[g + 1];
  float acc = 0.f;
  for (int n = s + half; n < e; n += 2) acc += hf[(size_t)n * CDIM + c];
  __shared__ float sb[2][128];
  __shared__ float sp[128], sz[64];
  sb[half][c] = acc;
  __syncthreads();
  float cg = fmaxf((float)(e - s), 1.f);
  if (t < 128) sp[t] = (sb[0][t] + sb[1][t]) / cg;
  __syncthreads();
  if (t < 64) {
    float a = bc1[t];
    for (int cc = 0; cc < 128; cc++) a += sp[cc] * Wc1[cc * 64 + t];
    sz[t] = fmaxf(a, 0.f);
  }
  __syncthreads();
  if (t < 64) {
    float pbv = sz[t] * Wc2[t];
    for (int off = 32; off; off >>= 1) pbv += __shfl_down(pbv, off, 64);
    if (t == 0) out[g] = pbv + bc2[0];
  }
}

// ---------------- host orchestration ----------------
extern "C" void kernel_launch(void* const* d_in, const int* in_sizes, int n_in,
                              void* d_out, int out_size, void* d_ws, size_t ws_size,
                              hipStream_t stream)
{
  if (n_in != 30) return;

  const int N = in_sizes[0];
  const int E = in_sizes[1] / 2;

  const int* x     = (const int*)d_in[0];
  const int* ei    = (const int*)d_in[1];
  const int* batch = (const int*)d_in[2];
  const float* emb = (const float*)d_in[3];
  const float* Wq0 = (const float*)d_in[4];  const float* bq0 = (const float*)d_in[5];
  const float* Wk0 = (const float*)d_in[6];  const float* bk0 = (const float*)d_in[7];
  const float* Wv0 = (const float*)d_in[8];  const float* bv0 = (const float*)d_in[9];
  const float* Ws0 = (const float*)d_in[10]; const float* bs0 = (const float*)d_in[11];
  const float* Wb0 = (const float*)d_in[12]; const float* g0  = (const float*)d_in[13]; const float* be0 = (const float*)d_in[14];
  const float* Wq1 = (const float*)d_in[15]; const float* bq1 = (const float*)d_in[16];
  const float* Wk1 = (const float*)d_in[17]; const float* bk1 = (const float*)d_in[18];
  const float* Wv1 = (const float*)d_in[19]; const float* bv1 = (const float*)d_in[20];
  const float* Ws1 = (const float*)d_in[21]; const float* bs1 = (const float*)d_in[22];
  const float* Wb1 = (const float*)d_in[23]; const float* g1  = (const float*)d_in[24]; const float* be1 = (const float*)d_in[25];
  const float* Wc1 = (const float*)d_in[26]; const float* bc1 = (const float*)d_in[27];
  const float* Wc2 = (const float*)d_in[28]; const float* bc2 = (const float*)d_in[29];

  auto rnd = [](size_t b) { return (b + 511) & ~(size_t)511; };
  size_t fixedBytes =
      rnd((size_t)N * CDIM * 4) +
      rnd((size_t)N * EMBD * 2) +
      rnd((size_t)N * CDIM * 2) * 2 +
      rnd((size_t)3 * HC * EMBD * 2) +
      rnd((size_t)3 * HC * CDIM * 2) +
      rnd((size_t)3 * HC * 4) * 2 +
      rnd((size_t)CDIM * EMBD * 2) +
      rnd((size_t)CDIM * CDIM * 2) +
      rnd((size_t)N * 4) * 2 +
      rnd((size_t)(N + 1) * 4) +
      rnd((size_t)E * 4) +
      rnd(256 * 4) +
      rnd(65 * 4);
  int hpc = 1;
  if (ws_size >= fixedBytes + rnd((size_t)N * 4 * 384 * 2)) hpc = 4;
  else if (ws_size >= fixedBytes + rnd((size_t)N * 2 * 384 * 2)) hpc = 2;
  const int chunkCols = hpc * 384;
  const int nchunks = HEADS / hpc;
  const int qkvTiles = chunkCols / 64;

  char* ws = (char*)d_ws;
  size_t off = 0;
  auto alloc = [&](size_t bytes) -> void* {
    void* p = ws + off;
    off += (bytes + 511) & ~(size_t)511;
    return p;
  };
  u16*   qkvc  = (u16*)  alloc((size_t)N * chunkCols * 2);  // tiled f16 per chunk
  float* outacc= (float*)alloc((size_t)N * CDIM * 4);
  u16*   h0    = (u16*)  alloc((size_t)N * EMBD * 2);       // layer-0 A; reused as f32 final features
  u16*   h1    = (u16*)  alloc((size_t)N * CDIM * 2);
  u16*   xrb   = (u16*)  alloc((size_t)N * CDIM * 2);       // tiled (2 tiles of 64), bf16
  u16*   WT0   = (u16*)  alloc((size_t)3 * HC * EMBD * 2);  // fragment-swizzled
  u16*   WT1   = (u16*)  alloc((size_t)3 * HC * CDIM * 2);
  float* bT0   = (float*)alloc((size_t)3 * HC * 4);
  float* bT1   = (float*)alloc((size_t)3 * HC * 4);
  u16*   WsT0  = (u16*)  alloc((size_t)CDIM * EMBD * 2);    // fragment-swizzled
  u16*   WsT1  = (u16*)  alloc((size_t)CDIM * CDIM * 2);
  int*   deg   = (int*)  alloc((size_t)N * 4);
  int*   fill  = (int*)  alloc((size_t)N * 4);
  int*   rowp  = (int*)  alloc((size_t)(N + 1) * 4);
  int*   colb  = (int*)  alloc((size_t)E * 4);
  int*   bsum  = (int*)  alloc(256 * 4);
  int*   gb    = (int*)  alloc(65 * 4);

  hipMemsetAsync(deg, 0, (size_t)N * 4, stream);
  hipMemsetAsync(fill, 0, (size_t)N * 4, stream);

  // prep
  embed_kernel<<<(N * 64 + 255) / 256, 256, 0, stream>>>(x, emb, h0, N);
  { dim3 gT(3 * HC / 128, EMBD / 64);
    build_qkvT_swz<<<gT, 256, 0, stream>>>(Wq0, Wk0, Wv0, WT0, EMBD, hpc); }
  { dim3 gT(3 * HC / 128, CDIM / 64);
    build_qkvT_swz<<<gT, 256, 0, stream>>>(Wq1, Wk1, Wv1, WT1, CDIM, hpc); }
  build_qkvb<<<(3 * HC + 255) / 256, 256, 0, stream>>>(bq0, bk0, bv0, bT0, hpc);
  build_qkvb<<<(3 * HC + 255) / 256, 256, 0, stream>>>(bq1, bk1, bv1, bT1, hpc);
  { dim3 gT(2, EMBD / 32);
    build_WsT_swz<<<gT, 256, 0, stream>>>(Ws0, WsT0, EMBD); }
  { dim3 gT(2, CDIM / 32);
    build_WsT_swz<<<gT, 256, 0, stream>>>(Ws1, WsT1, CDIM); }

  // CSR by dst + graph bounds
  int nb = (N + 255) / 256;
  deg_kernel<<<(E + 255) / 256, 256, 0, stream>>>(ei, deg, E);
  scan1_kernel<<<nb, 256, 0, stream>>>(deg, rowp, bsum, N);
  scan2_kernel<<<1, 256, 0, stream>>>(bsum, nb);
  scan3_kernel<<<nb, 256, 0, stream>>>(rowp, bsum, N);
  scatter_kernel<<<(E + 255) / 256, 256, 0, stream>>>(ei, rowp, fill, colb, E);
  gb_kernel<<<1, 128, 0, stream>>>(batch, gb, N);

  int rowStrips = (N + 63) / 64;
  int sGroups = (rowStrips + 7) / 8;
  float* hfinal = (float*)h0;
  int epiBlocks = (N + 1) / 2;

  if (hpc == 4) {
    // ---- fast path: 2 fused GEMMs + 2 attn + 1 epilogue per layer ----
    for (int layer = 0; layer < 2; layer++) {
      const u16* Ain   = (layer == 0) ? h0 : h1;
      const u16* WT    = (layer == 0) ? WT0 : WT1;
      const float* bT  = (layer == 0) ? bT0 : bT1;
      const u16* WsT   = (layer == 0) ? WsT0 : WsT1;
      const float* bs  = (layer == 0) ? bs0 : bs1;
      const float* Wb  = (layer == 0) ? Wb0 : Wb1;
      const float* gam = (layer == 0) ? g0 : g1;
      const float* bet = (layer == 0) ? be0 : be1;
      int K = (layer == 0) ? EMBD : CDIM;

      int nT0 = qkvTiles + 2;                      // chunk-0 + 2 XR tiles
      int nG0 = (nT0 + 3) / 4, nG1 = (qkvTiles + 3) / 4;
      int grid0 = sGroups * nG0 * 8, grid1 = sGroups * nG1 * 8;
      if (K == EMBD)
        gemm_lds<EMBD><<<grid0, 256, 0, stream>>>(Ain, WT, WsT, 0, qkvTiles, bT, bs, qkvc, xrb, N, nT0, rowStrips, nG0);
      else
        gemm_lds<CDIM><<<grid0, 256, 0, stream>>>(Ain, WT, WsT, 0, qkvTiles, bT, bs, qkvc, xrb, N, nT0, rowStrips, nG0);
      attn_chunk_kernel<4><<<N, 256, 0, stream>>>(qkvc, rowp, colb, outacc, N, 1);
      if (K == EMBD)
        gemm_lds<EMBD><<<grid1, 256, 0, stream>>>(Ain, WT, WsT, qkvTiles, 1 << 30, bT, bs, qkvc, xrb, N, qkvTiles, rowStrips, nG1);
      else
        gemm_lds<CDIM><<<grid1, 256, 0, stream>>>(Ain, WT, WsT, qkvTiles, 1 << 30, bT, bs, qkvc, xrb, N, qkvTiles, rowStrips, nG1);
      attn_chunk_kernel<4><<<N, 256, 0, stream>>>(qkvc, rowp, colb, outacc, N, 0);
      if (layer == 0)
        epilogue_kernel<0><<<epiBlocks, 256, 0, stream>>>(outacc, xrb, Wb, gam, bet,
                                                          (const u16*)nullptr, h1, (float*)nullptr, N);
      else
        epilogue_kernel<1><<<epiBlocks, 256, 0, stream>>>(outacc, xrb, Wb, gam, bet,
                                                          h1, (u16*)nullptr, hfinal, N);
    }
  } else {
    // ---- legacy fallback ----
    int attnBlocks = (hpc == 2) ? (N + 1) / 2 : (N + 3) / 4;
    for (int layer = 0; layer < 2; layer++) {
      const u16* Ain   = (layer == 0) ? h0 : h1;
      const u16* WT    = (layer == 0) ? WT0 : WT1;
      const float* bT  = (layer == 0) ? bT0 : bT1;
      const u16* WsT   = (layer == 0) ? WsT0 : WsT1;
      const float* bs  = (layer == 0) ? bs0 : bs1;
      const float* Wb  = (layer == 0) ? Wb0 : Wb1;
      const float* gam = (layer == 0) ? g0 : g1;
      const float* bet = (layer == 0) ? be0 : be1;
      int K = (layer == 0) ? EMBD : CDIM;

      int gridXR = sGroups * 1 * 8;
      int nG = (qkvTiles + 3) / 4;
      int gridQ = sGroups * nG * 8;
      if (K == EMBD) gemm_lds<EMBD><<<gridXR, 256, 0, stream>>>(Ain, WT, WsT, 0, 0, bT, bs, qkvc, xrb, N, 2, rowStrips, 1);
      else           gemm_lds<CDIM><<<gridXR, 256, 0, stream>>>(Ain, WT, WsT, 0, 0, bT, bs, qkvc, xrb, N, 2, rowStrips, 1);
      for (int c = 0; c < nchunks; c++) {
        int col0tile = c * qkvTiles;
        if (K == EMBD)
          gemm_lds<EMBD><<<gridQ, 256, 0, stream>>>(Ain, WT, WsT, col0tile, 1 << 30, bT, bs, qkvc, xrb, N, qkvTiles, rowStrips, nG);
        else
          gemm_lds<CDIM><<<gridQ, 256, 0, stream>>>(Ain, WT, WsT, col0tile, 1 << 30, bT, bs, qkvc, xrb, N, qkvTiles, rowStrips, nG);
        int first = (c == 0) ? 1 : 0;
        if (hpc == 2)
          attn_chunk_kernel<2><<<attnBlocks, 256, 0, stream>>>(qkvc, rowp, colb, outacc, N, first);
        else
          attn_chunk_kernel<1><<<attnBlocks, 256, 0, stream>>>(qkvc, rowp, colb, outacc, N, first);
      }
      if (layer == 0)
        epilogue_kernel<0><<<epiBlocks, 256, 0, stream>>>(outacc, xrb, Wb, gam, bet,
                                                          (const u16*)nullptr, h1, (float*)nullptr, N);
      else
        epilogue_kernel<1><<<epiBlocks, 256, 0, stream>>>(outacc, xrb, Wb, gam, bet,
                                                          h1, (u16*)nullptr, hfinal, N);
    }
  }

  classifier_kernel<<<NGRAPH, 256, 0, stream>>>(hfinal, gb, Wc1, bc1, Wc2, bc2,
                                                (float*)d_out);
}

// Round 15
// 1064.253 us; speedup vs baseline: 1.0465x; 1.0084x over previous
//
#include <hip/hip_runtime.h>
#include <hip/hip_fp16.h>
#include <math.h>

#define HEADS 8
#define CDIM 128
#define HC 1024
#define EMBD 256
#define NGRAPH 64
#define QSCALE2 0.12751744f             // (1/sqrt(128)) * log2(e): exp2-domain logits

typedef unsigned short u16;
typedef short s8v __attribute__((ext_vector_type(8)));
typedef float f4v __attribute__((ext_vector_type(4)));
typedef _Float16 h2v __attribute__((ext_vector_type(2)));

__device__ __forceinline__ float b2f(u16 u) {
  union { unsigned int i; float f; } v; v.i = ((unsigned int)u) << 16; return v.f;
}
__device__ __forceinline__ u16 f2b(float f) {
  union { float f; unsigned int i; } v; v.f = f;
  unsigned int i = v.i;
  unsigned int r = (i + 0x7FFFu + ((i >> 16) & 1u)) >> 16;
  return (u16)r;
}
__device__ __forceinline__ u16 f2h(float f) {
  __half h = __float2half(f);
  return *(u16*)&h;
}

union U4H { uint4 u; h2v h[4]; };

// ---------------- embedding gather + f32->bf16 ----------------
__global__ __launch_bounds__(256) void embed_kernel(
    const int* __restrict__ x, const float* __restrict__ emb,
    u16* __restrict__ h0, int N)
{
  int idx = blockIdx.x * 256 + threadIdx.x;
  if (idx >= N * (EMBD / 4)) return;
  int n = idx >> 6;
  int j = (idx & 63) * 4;
  int vid = x[n];
  float4 f = *(const float4*)&emb[(size_t)vid * EMBD + j];
  ushort4 u;
  u.x = f2b(f.x); u.y = f2b(f.y); u.z = f2b(f.z); u.w = f2b(f.w);
  *(ushort4*)&h0[(size_t)n * EMBD + j] = u;
}

// ---------------- Ws -> fragment-swizzled bf16 B ----------------
__global__ __launch_bounds__(256) void build_WsT_swz(
    const float* __restrict__ in, u16* __restrict__ out, int K)
{
  const int KS = K / 32;
  int nt = blockIdx.x;
  int ks = blockIdx.y;
  int t = threadIdx.x;
  int lane = t & 63, ni = t >> 6;
  int q4 = lane >> 4, cn = lane & 15;
  int colL = nt * 64 + ni * 16 + cn;
  int kbase = ks * 32 + q4 * 8;
  u16 tmp[8];
#pragma unroll
  for (int e8 = 0; e8 < 8; e8++) tmp[e8] = f2b(in[(size_t)(kbase + e8) * CDIM + colL]);
  size_t base = ((((size_t)nt * KS + ks) * 4 + ni) * 64 + lane) * 8;
  *(uint4*)&out[base] = *(uint4*)tmp;
}

// ---------------- chunked qkv^T weights -> fragment-swizzled bf16 (QSCALE2 in q) ----------------
__global__ __launch_bounds__(256) void build_qkvT_swz(
    const float* __restrict__ Wq, const float* __restrict__ Wk, const float* __restrict__ Wv,
    u16* __restrict__ WT, int K, int hpc)
{
  __shared__ u16 tile[64][130];
  const int KS = K / 32;
  int rg0 = blockIdx.x * 128;
  int kk0 = blockIdx.y * 64;
  int chunkCols = hpc * 384;
  int chunk = rg0 / chunkCols;
  int within = rg0 - chunk * chunkCols;
  int head = chunk * hpc + within / 384;
  int sub = within % 384;
  int sect = sub >> 7;
  const float* W = (sect == 0) ? Wq : (sect == 1 ? Wk : Wv);
  float scale = (sect == 0) ? QSCALE2 : 1.0f;
  int cc0 = head * CDIM;
  int t = threadIdx.x;
  int ci = t & 127, k2 = t >> 7;
#pragma unroll
  for (int ii = 0; ii < 32; ii++) {
    int ki = k2 + ii * 2;
    tile[ki][ci] = f2b(W[(size_t)(kk0 + ki) * HC + cc0 + ci] * scale);
  }
  __syncthreads();

  int lane = t & 63, ni = t >> 6;
  int q4 = lane >> 4, cn = lane & 15;
  int ntBase = rg0 >> 6;
#pragma unroll
  for (int ntd = 0; ntd < 2; ntd++) {
#pragma unroll
    for (int ksd = 0; ksd < 2; ksd++) {
      int colL = ntd * 64 + ni * 16 + cn;
      int kL = ksd * 32 + q4 * 8;
      u16 tmp[8];
#pragma unroll
      for (int e8 = 0; e8 < 8; e8++) tmp[e8] = tile[kL + e8][colL];
      size_t base = ((((size_t)(ntBase + ntd) * KS + (kk0 >> 5) + ksd) * 4 + ni) * 64 + lane) * 8;
      *(uint4*)&WT[base] = *(uint4*)tmp;
    }
  }
}
__global__ __launch_bounds__(256) void build_qkvb(
    const float* __restrict__ bq, const float* __restrict__ bk, const float* __restrict__ bv,
    float* __restrict__ bT, int hpc)
{
  int rg = blockIdx.x * 256 + threadIdx.x;
  if (rg >= 3 * HC) return;
  int chunkCols = hpc * 384;
  int chunk = rg / chunkCols;
  int within = rg - chunk * chunkCols;
  int head = chunk * hpc + within / 384;
  int sub = within % 384;
  int sect = sub >> 7;
  int cc = head * CDIM + (sub & 127);
  bT[rg] = (sect == 0) ? bq[cc] * QSCALE2 : (sect == 1 ? bk[cc] : bv[cc]);
}

// ---------------- CSR build ----------------
__global__ __launch_bounds__(256) void deg_kernel(const int* __restrict__ ei, int* __restrict__ deg, int E) {
  int e = blockIdx.x * 256 + threadIdx.x;
  if (e < E) atomicAdd(&deg[ei[E + e]], 1);
}
__global__ __launch_bounds__(256) void scan1_kernel(const int* __restrict__ deg, int* __restrict__ row_ptr,
                                                    int* __restrict__ bsum, int N) {
  __shared__ int sb[256];
  int t = threadIdx.x, idx = blockIdx.x * 256 + t;
  int x = (idx < N) ? deg[idx] : 0;
  sb[t] = x; __syncthreads();
  for (int off = 1; off < 256; off <<= 1) {
    int y = (t >= off) ? sb[t - off] : 0;
    __syncthreads(); sb[t] += y; __syncthreads();
  }
  if (idx < N) row_ptr[idx + 1] = sb[t];
  if (t == 255) bsum[blockIdx.x] = sb[255];
  if (idx == 0) row_ptr[0] = 0;
}
__global__ __launch_bounds__(256) void scan2_kernel(int* __restrict__ bsum, int B) {
  __shared__ int sb[256];
  int t = threadIdx.x;
  int x = (t < B) ? bsum[t] : 0;
  sb[t] = x; __syncthreads();
  for (int off = 1; off < 256; off <<= 1) {
    int y = (t >= off) ? sb[t - off] : 0;
    __syncthreads(); sb[t] += y; __syncthreads();
  }
  if (t < B) bsum[t] = sb[t] - x;   // exclusive
}
__global__ __launch_bounds__(256) void scan3_kernel(int* __restrict__ row_ptr, const int* __restrict__ bsum, int N) {
  int idx = blockIdx.x * 256 + threadIdx.x;
  if (idx < N) row_ptr[idx + 1] += bsum[idx >> 8];
}
__global__ __launch_bounds__(256) void scatter_kernel(const int* __restrict__ ei,
                                                      const int* __restrict__ row_ptr,
                                                      int* __restrict__ fill, int* __restrict__ col, int E) {
  int e = blockIdx.x * 256 + threadIdx.x;
  if (e >= E) return;
  int d = ei[E + e];
  int pos = row_ptr[d] + atomicAdd(&fill[d], 1);
  col[pos] = ei[e];
}
__global__ void gb_kernel(const int* __restrict__ batch, int* __restrict__ gb, int N) {
  int g = threadIdx.x;
  if (g > NGRAPH) return;
  int lo = 0, hi = N;
  while (lo < hi) { int mid = (lo + hi) >> 1; if (batch[mid] < g) lo = mid + 1; else hi = mid; }
  gb[g] = lo;
}

// ---------------- GEMM: A in LDS once; B fragment-swizzled from L2; XCD-swizzled grid ----------------
// qkv output now ROW-MAJOR per node: out[n][chunkCols] (node-major q|k|v per head).
template <int K>
__global__ __launch_bounds__(256, 3) void gemm_lds(
    const u16* __restrict__ A, const u16* __restrict__ Bq, const u16* __restrict__ Bx,
    int col0tile, int xrTile0,
    const float* __restrict__ biasQ, const float* __restrict__ biasX,
    u16* __restrict__ outQ, u16* __restrict__ outX,
    int M, int nTiles, int rowStrips, int nGroups, int outStrideQ)
{
  const int LDK = K + 8;
  const int KS = K / 32;
  __shared__ __align__(16) u16 As[64 * LDK];
  int B = blockIdx.x;
  int c8 = B & 7, kk = B >> 3;
  int tg = kk % nGroups;
  int s  = (kk / nGroups) * 8 + c8;
  if (s >= rowStrips) return;
  int t = threadIdx.x, lane = t & 63, w = t >> 6;
  int q4 = lane >> 4, cn = lane & 15;
  int m0 = s * 64;
  int ntL = tg * 4 + w;
  bool wActive = ntL < nTiles;
  int ntG = col0tile + ntL;
  bool isXr = ntG >= xrTile0;

  if (m0 + 64 <= M) {
    const u16* Ablk = A + (size_t)m0 * K;
#pragma unroll
    for (int ii = 0; ii < K / 32; ii++) {
      int g = (ii * 256 + t) * 8;
      int r = g / K, c = g - r * K;
      *(uint4*)&As[r * LDK + c] = *(const uint4*)(Ablk + g);
    }
  } else {
#pragma unroll
    for (int ii = 0; ii < K / 32; ii++) {
      int g = (ii * 256 + t) * 8;
      int r = g / K, c = g - r * K;
      int gr = m0 + r; if (gr >= M) gr = M - 1;
      *(uint4*)&As[r * LDK + c] = *(const uint4*)(A + (size_t)gr * K + c);
    }
  }
  __syncthreads();

  if (!wActive) return;

  f4v acc[4][4] = {};
  const u16* bb = isXr
      ? Bx + ((size_t)(ntG - xrTile0) * KS * 4) * 512 + lane * 8
      : Bq + ((size_t)ntG * KS * 4) * 512 + lane * 8;
#pragma unroll
  for (int ks = 0; ks < KS; ks++) {
    s8v bf[4], af[4];
#pragma unroll
    for (int ni = 0; ni < 4; ni++)
      bf[ni] = *(const s8v*)(bb + ((size_t)ks * 4 + ni) * 512);
#pragma unroll
    for (int mi = 0; mi < 4; mi++)
      af[mi] = *(const s8v*)&As[(mi * 16 + cn) * LDK + ks * 32 + q4 * 8];
#pragma unroll
    for (int mi = 0; mi < 4; mi++)
#pragma unroll
      for (int ni = 0; ni < 4; ni++)
        acc[mi][ni] = __builtin_amdgcn_mfma_f32_16x16x32_bf16(af[mi], bf[ni], acc[mi][ni], 0, 0, 0);
  }

  float bv[4];
#pragma unroll
  for (int ni = 0; ni < 4; ni++)
    bv[ni] = isXr ? biasX[(ntG - xrTile0) * 64 + ni * 16 + cn]
                  : biasQ[ntG * 64 + ni * 16 + cn];
  if (isXr) {
    u16* obase = outX + (size_t)(ntG - xrTile0) * M * 64;
#pragma unroll
    for (int mi = 0; mi < 4; mi++) {
#pragma unroll
      for (int j = 0; j < 4; j++) {
        int gm = m0 + mi * 16 + q4 * 4 + j;
        if (gm < M) {
#pragma unroll
          for (int ni = 0; ni < 4; ni++)
            obase[(size_t)gm * 64 + ni * 16 + cn] = f2b(acc[mi][ni][j] + bv[ni]);
        }
      }
    }
  } else {
    u16* obase = outQ + (size_t)ntL * 64;     // row-major: + gm*outStrideQ
#pragma unroll
    for (int mi = 0; mi < 4; mi++) {
#pragma unroll
      for (int j = 0; j < 4; j++) {
        int gm = m0 + mi * 16 + q4 * 4 + j;
        if (gm < M) {
#pragma unroll
          for (int ni = 0; ni < 4; ni++)
            obase[(size_t)gm * outStrideQ + ni * 16 + cn] = f2h(acc[mi][ni][j] + bv[ni]);
        }
      }
    }
  }
}

// ---------------- attention chunk: node-major qkv, 8 edges/trip, 16 lanes/edge ----------------
template <int HPC>
__global__ __launch_bounds__(256) void attn_chunk_kernel(
    const u16* __restrict__ qkv,
    const int* __restrict__ row_ptr, const int* __restrict__ col,
    float* __restrict__ outacc, int N, int first)
{
  const int STRIDE = HPC * 384;
  int t = threadIdx.x;
  int w = t >> 6, lane = t & 63;
  int g = lane >> 4, i = lane & 15;     // edge group 0..3, channel sub (8 ch/lane)
  int n, j;
  if (HPC == 4)      { n = blockIdx.x;                 j = w; }
  else if (HPC == 2) { n = blockIdx.x * 2 + (w >> 1);  j = w & 1; }
  else               { n = blockIdx.x * 4 + w;         j = 0; }
  bool active = (HPC == 4) ? true : (n < N);

  // node-major: node row = STRIDE u16; head j at +j*384; q|k|v at +0/+128/+256
  const u16* kb = qkv + j * 384 + 128 + i * 8;
  const u16* vb = qkv + j * 384 + 256 + i * 8;

  float acc[8] = {};
  float m = -INFINITY, l = 0.f;
  if (active) {
    U4H qu; qu.u = *(const uint4*)(qkv + (size_t)n * STRIDE + j * 384 + i * 8);
    int e0 = row_ptr[n], e1 = row_ptr[n + 1];
    for (int eb = e0; eb < e1; eb += 8) {
      int egA = eb + g, egB = eb + 4 + g;
      bool vA = egA < e1, vB = egB < e1;
      int sA = col[vA ? egA : e1 - 1];
      int sB = col[vB ? egB : e1 - 1];
      U4H kuA, vuA, kuB, vuB;
      kuA.u = *(const uint4*)(kb + (size_t)sA * STRIDE);
      kuB.u = *(const uint4*)(kb + (size_t)sB * STRIDE);
      vuA.u = *(const uint4*)(vb + (size_t)sA * STRIDE);
      vuB.u = *(const uint4*)(vb + (size_t)sB * STRIDE);

      float pA, pB;
#if defined(__has_builtin) && __has_builtin(__builtin_amdgcn_fdot2)
      pA = __builtin_amdgcn_fdot2(kuA.h[0], qu.h[0], 0.f, false);
      pA = __builtin_amdgcn_fdot2(kuA.h[1], qu.h[1], pA, false);
      pA = __builtin_amdgcn_fdot2(kuA.h[2], qu.h[2], pA, false);
      pA = __builtin_amdgcn_fdot2(kuA.h[3], qu.h[3], pA, false);
      pB = __builtin_amdgcn_fdot2(kuB.h[0], qu.h[0], 0.f, false);
      pB = __builtin_amdgcn_fdot2(kuB.h[1], qu.h[1], pB, false);
      pB = __builtin_amdgcn_fdot2(kuB.h[2], qu.h[2], pB, false);
      pB = __builtin_amdgcn_fdot2(kuB.h[3], qu.h[3], pB, false);
#else
      pA = 0.f; pB = 0.f;
#pragma unroll
      for (int z = 0; z < 4; z++) {
        pA += (float)kuA.h[z][0] * (float)qu.h[z][0] + (float)kuA.h[z][1] * (float)qu.h[z][1];
        pB += (float)kuB.h[z][0] * (float)qu.h[z][0] + (float)kuB.h[z][1] * (float)qu.h[z][1];
      }
#endif
#pragma unroll
      for (int off = 1; off <= 8; off <<= 1) {
        pA += __shfl_xor(pA, off, 64);
        pB += __shfl_xor(pB, off, 64);
      }
      if (!vA) pA = -INFINITY;
      if (!vB) pB = -INFINITY;

      float pm = fmaxf(pA, pB);
      pm = fmaxf(pm, __shfl_xor(pm, 16));
      pm = fmaxf(pm, __shfl_xor(pm, 32));
      if (pm > m) {
        float al = exp2f(m - pm);          // first trip: exp2(-inf)=0
        l *= al;
#pragma unroll
        for (int z = 0; z < 8; z++) acc[z] *= al;
        m = pm;
      }
      float peA = exp2f(pA - m);
      float peB = exp2f(pB - m);
      float ps = peA + peB;
      ps += __shfl_xor(ps, 16);
      ps += __shfl_xor(ps, 32);
      l += ps;
#pragma unroll
      for (int z = 0; z < 4; z++) {
        acc[2 * z]     = fmaf(peA, (float)vuA.h[z][0], acc[2 * z]);
        acc[2 * z + 1] = fmaf(peA, (float)vuA.h[z][1], acc[2 * z + 1]);
      }
#pragma unroll
      for (int z = 0; z < 4; z++) {
        acc[2 * z]     = fmaf(peB, (float)vuB.h[z][0], acc[2 * z]);
        acc[2 * z + 1] = fmaf(peB, (float)vuB.h[z][1], acc[2 * z + 1]);
      }
    }
  }
  float inv = 0.125f / (l + 1e-16f);      // head-mean folded in
#pragma unroll
  for (int z = 0; z < 8; z++) {
    float a = acc[z] * inv;
    a += __shfl_xor(a, 16);
    a += __shfl_xor(a, 32);
    acc[z] = a;
  }

  if (HPC == 1) {
    if (active && g == 0) {
      float* op = outacc + (size_t)n * CDIM + i * 8;
      if (first) {
        *(float4*)op       = make_float4(acc[0], acc[1], acc[2], acc[3]);
        *(float4*)(op + 4) = make_float4(acc[4], acc[5], acc[6], acc[7]);
      } else {
        float4 o0 = *(float4*)op, o1 = *(float4*)(op + 4);
        *(float4*)op       = make_float4(o0.x + acc[0], o0.y + acc[1], o0.z + acc[2], o0.w + acc[3]);
        *(float4*)(op + 4) = make_float4(o1.x + acc[4], o1.y + acc[5], o1.z + acc[6], o1.w + acc[7]);
      }
    }
  } else {
    __shared__ float sacc[4][128];
    if (g == 0) {
      *(float4*)&sacc[w][i * 8]     = make_float4(acc[0], acc[1], acc[2], acc[3]);
      *(float4*)&sacc[w][i * 8 + 4] = make_float4(acc[4], acc[5], acc[6], acc[7]);
    }
    __syncthreads();
    if (HPC == 4) {
      if (t < 128) {
        float v = sacc[0][t] + sacc[1][t] + sacc[2][t] + sacc[3][t];
        size_t o = (size_t)blockIdx.x * CDIM + t;
        outacc[o] = first ? v : (outacc[o] + v);
      }
    } else {
      int nn = blockIdx.x * 2 + (t >> 7);
      int c = t & 127;
      if (nn < N) {
        float v = sacc[(t >> 7) * 2][c] + sacc[(t >> 7) * 2 + 1][c];
        size_t o = (size_t)nn * CDIM + c;
        outacc[o] = first ? v : (outacc[o] + v);
      }
    }
  }
}

// ---------------- epilogue: beta gate + (residual) + LN + ReLU, 2 nodes/block ----------------
template <int LAYER>
__global__ __launch_bounds__(256) void epilogue_kernel(
    const float* __restrict__ outacc, const u16* __restrict__ xrT,
    const float* __restrict__ Wb, const float* __restrict__ gam, const float* __restrict__ bet,
    const u16* __restrict__ res,
    u16* __restrict__ hout, float* __restrict__ houtf, int N)
{
  int t = threadIdx.x;
  int local = t >> 7, c = t & 127, w = t >> 6;
  int n = blockIdx.x * 2 + local;
  bool act = n < N;
  __shared__ float sred[8];
  __shared__ float smv[2][3];

  float oc = 0.f, xc = 0.f;
  if (act) {
    oc = outacc[(size_t)n * CDIM + c];
    xc = b2f(xrT[((size_t)(c >> 6) * N + n) * 64 + (c & 63)]);
  }
  float pb = oc * Wb[c] + xc * Wb[CDIM + c] + (oc - xc) * Wb[2 * CDIM + c];
#pragma unroll
  for (int off = 32; off; off >>= 1) pb += __shfl_down(pb, off, 64);
  if ((t & 63) == 0) sred[w] = pb;
  __syncthreads();
  if (t == 0)   smv[0][0] = 1.f / (1.f + __expf(-(sred[0] + sred[1])));
  if (t == 128) smv[1][0] = 1.f / (1.f + __expf(-(sred[2] + sred[3])));
  __syncthreads();
  float beta = smv[local][0];
  float val = beta * xc + (1.f - beta) * oc;
  if (LAYER == 1 && act) val += b2f(res[(size_t)n * CDIM + c]);

  float s1 = val, s2 = val * val;
#pragma unroll
  for (int off = 32; off; off >>= 1) {
    s1 += __shfl_down(s1, off, 64);
    s2 += __shfl_down(s2, off, 64);
  }
  __syncthreads();
  if ((t & 63) == 0) { sred[w * 2] = s1; sred[w * 2 + 1] = s2; }
  __syncthreads();
  if (t == 0) {
    float S1 = sred[0] + sred[2], S2 = sred[1] + sred[3];
    float mu = S1 * (1.f / CDIM);
    float var = fmaxf(S2 * (1.f / CDIM) - mu * mu, 0.f);
    smv[0][1] = mu; smv[0][2] = 1.f / sqrtf(var + 1e-5f);
  }
  if (t == 128) {
    float S1 = sred[4] + sred[6], S2 = sred[5] + sred[7];
    float mu = S1 * (1.f / CDIM);
    float var = fmaxf(S2 * (1.f / CDIM) - mu * mu, 0.f);
    smv[1][1] = mu; smv[1][2] = 1.f / sqrtf(var + 1e-5f);
  }
  __syncthreads();
  if (act) {
    float y = (val - smv[local][1]) * smv[local][2] * gam[c] + bet[c];
    y = fmaxf(y, 0.f);
    if (LAYER == 0) hout[(size_t)n * CDIM + c] = f2b(y);
    else            houtf[(size_t)n * CDIM + c] = y;
  }
}

// ---------------- fused pool + classifier: one block per graph ----------------
__global__ __launch_bounds__(256) void classifier_kernel(
    const float* __restrict__ hf, const int* __restrict__ gb,
    const float* __restrict__ Wc1, const float* __restrict__ bc1,
    const float* __restrict__ Wc2, const float* __restrict__ bc2,
    float* __restrict__ out)
{
  int g = blockIdx.x, t = threadIdx.x;
  int half = t >> 7, c = t & 127;
  int s = gb[g], e = gb[g + 1];
  float acc = 0.f;
  for (int n = s + half; n < e; n += 2) acc += hf[(size_t)n * CDIM + c];
  __shared__ float sb[2][128];
  __shared__ float sp[128], sz[64];
  sb[half][c] = acc;
  __syncthreads();
  float cg = fmaxf((float)(e - s), 1.f);
  if (t < 128) sp[t] = (sb[0][t] + sb[1][t]) / cg;
  __syncthreads();
  if (t < 64) {
    float a = bc1[t];
    for (int cc = 0; cc < 128; cc++) a += sp[cc] * Wc1[cc * 64 + t];
    sz[t] = fmaxf(a, 0.f);
  }
  __syncthreads();
  if (t < 64) {
    float pbv = sz[t] * Wc2[t];
    for (int off = 32; off; off >>= 1) pbv += __shfl_down(pbv, off, 64);
    if (t == 0) out[g] = pbv + bc2[0];
  }
}

// ---------------- host orchestration ----------------
extern "C" void kernel_launch(void* const* d_in, const int* in_sizes, int n_in,
                              void* d_out, int out_size, void* d_ws, size_t ws_size,
                              hipStream_t stream)
{
  if (n_in != 30) return;

  const int N = in_sizes[0];
  const int E = in_sizes[1] / 2;

  const int* x     = (const int*)d_in[0];
  const int* ei    = (const int*)d_in[1];
  const int* batch = (const int*)d_in[2];
  const float* emb = (const float*)d_in[3];
  const float* Wq0 = (const float*)d_in[4];  const float* bq0 = (const float*)d_in[5];
  const float* Wk0 = (const float*)d_in[6];  const float* bk0 = (const float*)d_in[7];
  const float* Wv0 = (const float*)d_in[8];  const float* bv0 = (const float*)d_in[9];
  const float* Ws0 = (const float*)d_in[10]; const float* bs0 = (const float*)d_in[11];
  const float* Wb0 = (const float*)d_in[12]; const float* g0  = (const float*)d_in[13]; const float* be0 = (const float*)d_in[14];
  const float* Wq1 = (const float*)d_in[15]; const float* bq1 = (const float*)d_in[16];
  const float* Wk1 = (const float*)d_in[17]; const float* bk1 = (const float*)d_in[18];
  const float* Wv1 = (const float*)d_in[19]; const float* bv1 = (const float*)d_in[20];
  const float* Ws1 = (const float*)d_in[21]; const float* bs1 = (const float*)d_in[22];
  const float* Wb1 = (const float*)d_in[23]; const float* g1  = (const float*)d_in[24]; const float* be1 = (const float*)d_in[25];
  const float* Wc1 = (const float*)d_in[26]; const float* bc1 = (const float*)d_in[27];
  const float* Wc2 = (const float*)d_in[28]; const float* bc2 = (const float*)d_in[29];

  auto rnd = [](size_t b) { return (b + 511) & ~(size_t)511; };
  size_t fixedBytes =
      rnd((size_t)N * CDIM * 4) +
      rnd((size_t)N * EMBD * 2) +
      rnd((size_t)N * CDIM * 2) * 2 +
      rnd((size_t)3 * HC * EMBD * 2) +
      rnd((size_t)3 * HC * CDIM * 2) +
      rnd((size_t)3 * HC * 4) * 2 +
      rnd((size_t)CDIM * EMBD * 2) +
      rnd((size_t)CDIM * CDIM * 2) +
      rnd((size_t)N * 4) * 2 +
      rnd((size_t)(N + 1) * 4) +
      rnd((size_t)E * 4) +
      rnd(256 * 4) +
      rnd(65 * 4);
  int hpc = 1;
  if (ws_size >= fixedBytes + rnd((size_t)N * 4 * 384 * 2)) hpc = 4;
  else if (ws_size >= fixedBytes + rnd((size_t)N * 2 * 384 * 2)) hpc = 2;
  const int chunkCols = hpc * 384;
  const int nchunks = HEADS / hpc;
  const int qkvTiles = chunkCols / 64;

  char* ws = (char*)d_ws;
  size_t off = 0;
  auto alloc = [&](size_t bytes) -> void* {
    void* p = ws + off;
    off += (bytes + 511) & ~(size_t)511;
    return p;
  };
  u16*   qkvc  = (u16*)  alloc((size_t)N * chunkCols * 2);  // node-major f16 per chunk
  float* outacc= (float*)alloc((size_t)N * CDIM * 4);
  u16*   h0    = (u16*)  alloc((size_t)N * EMBD * 2);       // layer-0 A; reused as f32 final features
  u16*   h1    = (u16*)  alloc((size_t)N * CDIM * 2);
  u16*   xrb   = (u16*)  alloc((size_t)N * CDIM * 2);       // tiled (2 tiles of 64), bf16
  u16*   WT0   = (u16*)  alloc((size_t)3 * HC * EMBD * 2);  // fragment-swizzled
  u16*   WT1   = (u16*)  alloc((size_t)3 * HC * CDIM * 2);
  float* bT0   = (float*)alloc((size_t)3 * HC * 4);
  float* bT1   = (float*)alloc((size_t)3 * HC * 4);
  u16*   WsT0  = (u16*)  alloc((size_t)CDIM * EMBD * 2);    // fragment-swizzled
  u16*   WsT1  = (u16*)  alloc((size_t)CDIM * CDIM * 2);
  int*   deg   = (int*)  alloc((size_t)N * 4);
  int*   fill  = (int*)  alloc((size_t)N * 4);
  int*   rowp  = (int*)  alloc((size_t)(N + 1) * 4);
  int*   colb  = (int*)  alloc((size_t)E * 4);
  int*   bsum  = (int*)  alloc(256 * 4);
  int*   gb    = (int*)  alloc(65 * 4);

  hipMemsetAsync(deg, 0, (size_t)N * 4, stream);
  hipMemsetAsync(fill, 0, (size_t)N * 4, stream);

  // prep
  embed_kernel<<<(N * 64 + 255) / 256, 256, 0, stream>>>(x, emb, h0, N);
  { dim3 gT(3 * HC / 128, EMBD / 64);
    build_qkvT_swz<<<gT, 256, 0, stream>>>(Wq0, Wk0, Wv0, WT0, EMBD, hpc); }
  { dim3 gT(3 * HC / 128, CDIM / 64);
    build_qkvT_swz<<<gT, 256, 0, stream>>>(Wq1, Wk1, Wv1, WT1, CDIM, hpc); }
  build_qkvb<<<(3 * HC + 255) / 256, 256, 0, stream>>>(bq0, bk0, bv0, bT0, hpc);
  build_qkvb<<<(3 * HC + 255) / 256, 256, 0, stream>>>(bq1, bk1, bv1, bT1, hpc);
  { dim3 gT(2, EMBD / 32);
    build_WsT_swz<<<gT, 256, 0, stream>>>(Ws0, WsT0, EMBD); }
  { dim3 gT(2, CDIM / 32);
    build_WsT_swz<<<gT, 256, 0, stream>>>(Ws1, WsT1, CDIM); }

  // CSR by dst + graph bounds
  int nb = (N + 255) / 256;
  deg_kernel<<<(E + 255) / 256, 256, 0, stream>>>(ei, deg, E);
  scan1_kernel<<<nb, 256, 0, stream>>>(deg, rowp, bsum, N);
  scan2_kernel<<<1, 256, 0, stream>>>(bsum, nb);
  scan3_kernel<<<nb, 256, 0, stream>>>(rowp, bsum, N);
  scatter_kernel<<<(E + 255) / 256, 256, 0, stream>>>(ei, rowp, fill, colb, E);
  gb_kernel<<<1, 128, 0, stream>>>(batch, gb, N);

  int rowStrips = (N + 63) / 64;
  int sGroups = (rowStrips + 7) / 8;
  float* hfinal = (float*)h0;
  int epiBlocks = (N + 1) / 2;

  if (hpc == 4) {
    for (int layer = 0; layer < 2; layer++) {
      const u16* Ain   = (layer == 0) ? h0 : h1;
      const u16* WT    = (layer == 0) ? WT0 : WT1;
      const float* bT  = (layer == 0) ? bT0 : bT1;
      const u16* WsT   = (layer == 0) ? WsT0 : WsT1;
      const float* bs  = (layer == 0) ? bs0 : bs1;
      const float* Wb  = (layer == 0) ? Wb0 : Wb1;
      const float* gam = (layer == 0) ? g0 : g1;
      const float* bet = (layer == 0) ? be0 : be1;
      int K = (layer == 0) ? EMBD : CDIM;

      int nT0 = qkvTiles + 2;                      // chunk-0 + 2 XR tiles
      int nG0 = (nT0 + 3) / 4, nG1 = (qkvTiles + 3) / 4;
      int grid0 = sGroups * nG0 * 8, grid1 = sGroups * nG1 * 8;
      if (K == EMBD)
        gemm_lds<EMBD><<<grid0, 256, 0, stream>>>(Ain, WT, WsT, 0, qkvTiles, bT, bs, qkvc, xrb, N, nT0, rowStrips, nG0, chunkCols);
      else
        gemm_lds<CDIM><<<grid0, 256, 0, stream>>>(Ain, WT, WsT, 0, qkvTiles, bT, bs, qkvc, xrb, N, nT0, rowStrips, nG0, chunkCols);
      attn_chunk_kernel<4><<<N, 256, 0, stream>>>(qkvc, rowp, colb, outacc, N, 1);
      if (K == EMBD)
        gemm_lds<EMBD><<<grid1, 256, 0, stream>>>(Ain, WT, WsT, qkvTiles, 1 << 30, bT, bs, qkvc, xrb, N, qkvTiles, rowStrips, nG1, chunkCols);
      else
        gemm_lds<CDIM><<<grid1, 256, 0, stream>>>(Ain, WT, WsT, qkvTiles, 1 << 30, bT, bs, qkvc, xrb, N, qkvTiles, rowStrips, nG1, chunkCols);
      attn_chunk_kernel<4><<<N, 256, 0, stream>>>(qkvc, rowp, colb, outacc, N, 0);
      if (layer == 0)
        epilogue_kernel<0><<<epiBlocks, 256, 0, stream>>>(outacc, xrb, Wb, gam, bet,
                                                          (const u16*)nullptr, h1, (float*)nullptr, N);
      else
        epilogue_kernel<1><<<epiBlocks, 256, 0, stream>>>(outacc, xrb, Wb, gam, bet,
                                                          h1, (u16*)nullptr, hfinal, N);
    }
  } else {
    int attnBlocks = (hpc == 2) ? (N + 1) / 2 : (N + 3) / 4;
    for (int layer = 0; layer < 2; layer++) {
      const u16* Ain   = (layer == 0) ? h0 : h1;
      const u16* WT    = (layer == 0) ? WT0 : WT1;
      const float* bT  = (layer == 0) ? bT0 : bT1;
      const u16* WsT   = (layer == 0) ? WsT0 : WsT1;
      const float* bs  = (layer == 0) ? bs0 : bs1;
      const float* Wb  = (layer == 0) ? Wb0 : Wb1;
      const float* gam = (layer == 0) ? g0 : g1;
      const float* bet = (layer == 0) ? be0 : be1;
      int K = (layer == 0) ? EMBD : CDIM;

      int gridXR = sGroups * 1 * 8;
      int nG = (qkvTiles + 3) / 4;
      int gridQ = sGroups * nG * 8;
      if (K == EMBD) gemm_lds<EMBD><<<gridXR, 256, 0, stream>>>(Ain, WT, WsT, 0, 0, bT, bs, qkvc, xrb, N, 2, rowStrips, 1, chunkCols);
      else           gemm_lds<CDIM><<<gridXR, 256, 0, stream>>>(Ain, WT, WsT, 0, 0, bT, bs, qkvc, xrb, N, 2, rowStrips, 1, chunkCols);
      for (int c = 0; c < nchunks; c++) {
        int col0tile = c * qkvTiles;
        if (K == EMBD)
          gemm_lds<EMBD><<<gridQ, 256, 0, stream>>>(Ain, WT, WsT, col0tile, 1 << 30, bT, bs, qkvc, xrb, N, qkvTiles, rowStrips, nG, chunkCols);
        else
          gemm_lds<CDIM><<<gridQ, 256, 0, stream>>>(Ain, WT, WsT, col0tile, 1 << 30, bT, bs, qkvc, xrb, N, qkvTiles, rowStrips, nG, chunkCols);
        int first = (c == 0) ? 1 : 0;
        if (hpc == 2)
          attn_chunk_kernel<2><<<attnBlocks, 256, 0, stream>>>(qkvc, rowp, colb, outacc, N, first);
        else
          attn_chunk_kernel<1><<<attnBlocks, 256, 0, stream>>>(qkvc, rowp, colb, outacc, N, first);
      }
      if (layer == 0)
        epilogue_kernel<0><<<epiBlocks, 256, 0, stream>>>(outacc, xrb, Wb, gam, bet,
                                                          (const u16*)nullptr, h1, (float*)nullptr, N);
      else
        epilogue_kernel<1><<<epiBlocks, 256, 0, stream>>>(outacc, xrb, Wb, gam, bet,
                                                          h1, (u16*)nullptr, hfinal, N);
    }
  }

  classifier_kernel<<<NGRAPH, 256, 0, stream>>>(hfinal, gb, Wc1, bc1, Wc2, bc2,
                                                (float*)d_out);
}